// Round 2
// baseline (4218.518 us; speedup 1.0000x reference)
//
#include <hip/hip_runtime.h>

// DecoderWithAttention: B=16, T=32, F=8, S_ENC=256, H=512, L=2.
// Persistent cooperative-style kernel (own atomic barrier), fp32 everywhere.
// 256 blocks x 256 threads; blocks grouped as (b = bid>>4, g = bid&15).
// Per step: S2 (hid_proj reduce + scores + softmax partials) -> barrier ->
//           S3 (weighted combine + GRU0 row-slice)           -> barrier ->
//           S4 (GRU1 row-slice + next hid_proj partials + out partials) -> barrier.
// enc-side attention projection (enc_proj) precomputed once in prologue.
//
// R1 fix: the grid barrier now spins with RELAXED atomics and issues exactly
// ONE release fence (before arrive) and ONE acquire fence (after spin exit)
// per block per barrier. R0 polled with ACQUIRE -> a buffer_inv per poll per
// block -> continuous L1/L2 invalidation (4.5 ms; intermittent staleness).

namespace {
constexpr int kB = 16, kT = 32, kF = 8, kS = 256, kH = 512;
constexpr int NBLK = 256, NTHR = 256;

// workspace layout in floats (ws[0] = barrier counter, zeroed via hipMemsetAsync)
constexpr int OFF_WENCT = 64;                         // [512][512]  attn_W[:,512:].T
constexpr int OFF_WHIDT = OFF_WENCT + kH * kH;        // [512][512]  attn_W[:,:512].T
constexpr int OFF_ENCP  = OFF_WHIDT + kH * kH;        // [B][S][H]   enc projection + bias
constexpr int OFF_HIDP  = OFF_ENCP + kB * kS * kH;    // [16][B][H]  hid_proj partials (by k-slice g)
constexpr int OFF_PWP   = OFF_HIDP + 16 * kB * kH;    // [B][16][H]  weighted partials
constexpr int OFF_MP    = OFF_PWP + kB * 16 * kH;     // [B][16]     softmax slice max
constexpr int OFF_LP    = OFF_MP + kB * 16;           // [B][16]     softmax slice expsum
constexpr int OFF_H0    = OFF_LP + kB * 16;           // [2][B][H]   h0 double buffer
constexpr int OFF_H1    = OFF_H0 + 2 * kB * kH;       // [2][B][H]   h1 double buffer
constexpr int OFF_WEI   = OFF_H1 + 2 * kB * kH;       // [B][H]      weighted (full)
constexpr int OFF_XIN   = OFF_WEI + kB * kH;          // [B][F]      current x_in
constexpr int OFF_OUTP  = OFF_XIN + kB * kF;          // [B][16][F]  out partials (h1 slices)
constexpr int OFF_OUTB  = OFF_OUTP + kB * 16 * kF;    // [B][F]      out base term
}  // namespace

__device__ __forceinline__ float fsig(float x) { return 1.0f / (1.0f + __expf(-x)); }
__device__ __forceinline__ float ftanhf(float x) {
    float e = __expf(2.0f * x);
    return 1.0f - 2.0f / (e + 1.0f);
}

__device__ __forceinline__ void gbar(unsigned* cnt, unsigned& barcount) {
    __syncthreads();
    ++barcount;
    if (threadIdx.x == 0) {
        // Publish this block's stores to device scope ONCE (writeback), then
        // arrive with a relaxed add. ("" = system scope: strongest available.)
        __builtin_amdgcn_fence(__ATOMIC_RELEASE, "");
        __hip_atomic_fetch_add(cnt, 1u, __ATOMIC_RELAXED, __HIP_MEMORY_SCOPE_SYSTEM);
        const unsigned target = barcount * (unsigned)NBLK;
        // Relaxed polling: no cache-invalidate per poll.
        while (__hip_atomic_load(cnt, __ATOMIC_RELAXED, __HIP_MEMORY_SCOPE_SYSTEM) < target)
            __builtin_amdgcn_s_sleep(8);
        // One acquire (invalidate) now that all blocks have arrived.
        __builtin_amdgcn_fence(__ATOMIC_ACQUIRE, "");
    }
    __syncthreads();
}

__global__ __launch_bounds__(NTHR) void decoder_kernel(
    const float* __restrict__ target, const float* __restrict__ hidden0,
    const float* __restrict__ enc, const float* __restrict__ attn_W,
    const float* __restrict__ attn_b, const float* __restrict__ v_w,
    const float* __restrict__ Wih0, const float* __restrict__ Whh0,
    const float* __restrict__ bih0, const float* __restrict__ bhh0,
    const float* __restrict__ Wih1, const float* __restrict__ Whh1,
    const float* __restrict__ bih1, const float* __restrict__ bhh1,
    const float* __restrict__ outW, const float* __restrict__ outBias,
    float* __restrict__ out, float* __restrict__ ws) {
    const int tid = threadIdx.x;
    const int bid = blockIdx.x;
    const int b = bid >> 4;
    const int g = bid & 15;
    unsigned barcount = 0;
    unsigned* cnt = (unsigned*)ws;

    float* WencT = ws + OFF_WENCT;
    float* WhidT = ws + OFF_WHIDT;
    float* encp  = ws + OFF_ENCP;
    float* hidP  = ws + OFF_HIDP;
    float* pwP   = ws + OFF_PWP;
    float* mP    = ws + OFF_MP;
    float* lP    = ws + OFF_LP;
    float* h0buf = ws + OFF_H0;
    float* h1buf = ws + OFF_H1;
    float* weiG  = ws + OFF_WEI;
    float* xin   = ws + OFF_XIN;
    float* outP  = ws + OFF_OUTP;
    float* outBs = ws + OFF_OUTB;

    __shared__ float lds[8192];  // 32 KB; repurposed per stage

    // ================= P0a: transposes + state init + initial hid_proj partials =======
    {
        // WencT[k][j] = attn_W[j][512+k]; WhidT[k][j] = attn_W[j][k]
        for (int kk = 0; kk < 2; ++kk) {
            const int k = bid * 2 + kk;
            for (int jj = 0; jj < 2; ++jj) {
                const int j = tid + jj * 256;
                WencT[k * kH + j] = attn_W[j * 1024 + 512 + k];
                WhidT[k * kH + j] = attn_W[j * 1024 + k];
            }
        }
        if (g == 0 && tid < kF) xin[b * kF + tid] = target[b * kT * kF + tid];
        if (tid < 32) {
            const int j = g * 32 + tid;
            h0buf[b * kH + j] = hidden0[0 * kB * kH + b * kH + j];
            h1buf[b * kH + j] = hidden0[1 * kB * kH + b * kH + j];
        }
        // hidP[(g*B+b)][j] = sum_{k in g-slice} h1_init[b][k] * attn_W[j][k]
        const float* h1i = hidden0 + kB * kH + b * kH + g * 32;
        for (int jj = 0; jj < 2; ++jj) {
            const int j = tid + jj * 256;
            const float* wrow = attn_W + j * 1024 + g * 32;
            float acc = 0.f;
#pragma unroll
            for (int k = 0; k < 32; ++k) acc += h1i[k] * wrow[k];
            hidP[(g * kB + b) * kH + j] = acc;
        }
    }
    gbar(cnt, barcount);

    // ================= P0b: enc_proj = enc @ WencT + attn_b ===========================
    {
        const int r0 = bid * 16;  // 16 rows of the 4096 (b,s) rows
        for (int idx = tid; idx < 16 * kH; idx += NTHR) {
            const int r = idx >> 9, k = idx & 511;
            lds[idx] = enc[(r0 + r) * kH + k];
        }
        __syncthreads();
        float acc0[16], acc1[16];
#pragma unroll
        for (int r = 0; r < 16; ++r) { acc0[r] = 0.f; acc1[r] = 0.f; }
        for (int k = 0; k < kH; ++k) {
            const float w0 = WencT[k * kH + tid];
            const float w1 = WencT[k * kH + tid + 256];
#pragma unroll
            for (int r = 0; r < 16; ++r) {
                const float e = lds[r * kH + k];
                acc0[r] += e * w0;
                acc1[r] += e * w1;
            }
        }
        const float b0 = attn_b[tid], b1 = attn_b[tid + 256];
#pragma unroll
        for (int r = 0; r < 16; ++r) {
            encp[(r0 + r) * kH + tid] = acc0[r] + b0;
            encp[(r0 + r) * kH + tid + 256] = acc1[r] + b1;
        }
    }
    gbar(cnt, barcount);

    // ================= main 32-step recurrence ========================================
    float* scoresL = lds + 512;  // [16]
    float* ewL = lds + 528;      // [16]
    for (int t = 0; t < kT; ++t) {
        const int par = t & 1;
        const float* h0old = h0buf + par * kB * kH;
        float* h0new = h0buf + (par ^ 1) * kB * kH;
        const float* h1old = h1buf + par * kB * kH;
        float* h1new = h1buf + (par ^ 1) * kB * kH;

        // ---------- S2: hid_proj reduce + scores + softmax partials ----------
        for (int jj = 0; jj < 2; ++jj) {
            const int j = tid + jj * 256;
            float acc = 0.f;
#pragma unroll
            for (int gg = 0; gg < 16; ++gg) acc += hidP[(gg * kB + b) * kH + j];
            lds[j] = acc;
        }
        if (t > 0 && g == 0 && tid < kF) {  // reduce previous step's output
            float o = outBs[b * kF + tid];
#pragma unroll
            for (int gg = 0; gg < 16; ++gg) o += outP[(b * 16 + gg) * kF + tid];
            o = fmaxf(o, 0.f);
            out[b * kT * kF + (t - 1) * kF + tid] = o;
            xin[b * kF + tid] = o;
        }
        __syncthreads();
        {
            const int sgrp = tid >> 4, lane = tid & 15;
            const int s = g * 16 + sgrp;
            const float* ep = encp + (b * kS + s) * kH;
            float acc = 0.f;
            for (int j = lane; j < kH; j += 16) acc += v_w[j] * ftanhf(ep[j] + lds[j]);
#pragma unroll
            for (int d = 8; d > 0; d >>= 1) acc += __shfl_down(acc, d, 16);
            if (lane == 0) scoresL[sgrp] = acc;
        }
        __syncthreads();
        {
            float m = -1e30f;
#pragma unroll
            for (int i = 0; i < 16; ++i) m = fmaxf(m, scoresL[i]);
            float l = 0.f;
#pragma unroll
            for (int i = 0; i < 16; ++i) l += __expf(scoresL[i] - m);
            if (tid < 16) ewL[tid] = __expf(scoresL[tid] - m);
            if (tid == 0) { mP[b * 16 + g] = m; lP[b * 16 + g] = l; }
        }
        __syncthreads();
        for (int jj = 0; jj < 2; ++jj) {
            const int j = tid + jj * 256;
            float acc = 0.f;
#pragma unroll
            for (int i = 0; i < 16; ++i) acc += ewL[i] * enc[(b * kS + g * 16 + i) * kH + j];
            pwP[(b * 16 + g) * kH + j] = acc;
        }
        gbar(cnt, barcount);

        // ---------- S3: weighted combine + GRU layer 0 ----------
        {
            float c[16];
            float M = -1e30f;
#pragma unroll
            for (int gg = 0; gg < 16; ++gg) M = fmaxf(M, mP[b * 16 + gg]);
            float denom = 0.f;
#pragma unroll
            for (int gg = 0; gg < 16; ++gg) {
                c[gg] = __expf(mP[b * 16 + gg] - M);
                denom += lP[b * 16 + gg] * c[gg];
            }
            const float inv = 1.f / denom;
#pragma unroll
            for (int gg = 0; gg < 16; ++gg) c[gg] *= inv;
            float* xL = lds;         // [520]: x = [x_in, weighted]
            float* hL = lds + 576;   // [512]: h0_old
            for (int jj = 0; jj < 2; ++jj) {
                const int j = tid + jj * 256;
                float acc = 0.f;
#pragma unroll
                for (int gg = 0; gg < 16; ++gg) acc += c[gg] * pwP[(b * 16 + gg) * kH + j];
                xL[kF + j] = acc;
                if (g == 0) weiG[b * kH + j] = acc;
                hL[j] = h0old[b * kH + j];
            }
            if (tid < kF) xL[tid] = xin[b * kF + tid];
            __syncthreads();
            const int rr = tid >> 3, sub = tid & 7;
            const int jj = g * 32 + rr;
            const float* wr = Wih0 + jj * 520;
            const float* wz = Wih0 + (512 + jj) * 520;
            const float* wn = Wih0 + (1024 + jj) * 520;
            float ar = 0.f, az = 0.f, an = 0.f;
            for (int k = sub; k < 520; k += 8) {
                const float xv = xL[k];
                ar += xv * wr[k]; az += xv * wz[k]; an += xv * wn[k];
            }
            const float* ur = Whh0 + jj * kH;
            const float* uz = Whh0 + (512 + jj) * kH;
            const float* un = Whh0 + (1024 + jj) * kH;
            float hr = 0.f, hz = 0.f, hn = 0.f;
            for (int k = sub; k < kH; k += 8) {
                const float hv = hL[k];
                hr += hv * ur[k]; hz += hv * uz[k]; hn += hv * un[k];
            }
#pragma unroll
            for (int d = 4; d > 0; d >>= 1) {
                ar += __shfl_down(ar, d, 8); az += __shfl_down(az, d, 8);
                an += __shfl_down(an, d, 8); hr += __shfl_down(hr, d, 8);
                hz += __shfl_down(hz, d, 8); hn += __shfl_down(hn, d, 8);
            }
            if (sub == 0) {
                const float r = fsig(ar + bih0[jj] + hr + bhh0[jj]);
                const float z = fsig(az + bih0[512 + jj] + hz + bhh0[512 + jj]);
                const float n = ftanhf(an + bih0[1024 + jj] + r * (hn + bhh0[1024 + jj]));
                h0new[b * kH + jj] = (1.f - z) * n + z * hL[jj];
            }
        }
        gbar(cnt, barcount);

        // ---------- S4: GRU layer 1 + next hid_proj partials + out partials ----------
        {
            float* xL = lds;          // [512]: h0_new
            float* hL = lds + 576;    // [512]: h1_old
            float* h1sL = lds + 1152; // [32]:  this block's h1_new slice
            for (int jj = 0; jj < 2; ++jj) {
                const int j = tid + jj * 256;
                xL[j] = h0new[b * kH + j];
                hL[j] = h1old[b * kH + j];
            }
            __syncthreads();
            const int rr = tid >> 3, sub = tid & 7;
            const int jj = g * 32 + rr;
            const float* wr = Wih1 + jj * kH;
            const float* wz = Wih1 + (512 + jj) * kH;
            const float* wn = Wih1 + (1024 + jj) * kH;
            const float* ur = Whh1 + jj * kH;
            const float* uz = Whh1 + (512 + jj) * kH;
            const float* un = Whh1 + (1024 + jj) * kH;
            float ar = 0.f, az = 0.f, an = 0.f, hr = 0.f, hz = 0.f, hn = 0.f;
            for (int k = sub; k < kH; k += 8) {
                const float xv = xL[k], hv = hL[k];
                ar += xv * wr[k]; az += xv * wz[k]; an += xv * wn[k];
                hr += hv * ur[k]; hz += hv * uz[k]; hn += hv * un[k];
            }
#pragma unroll
            for (int d = 4; d > 0; d >>= 1) {
                ar += __shfl_down(ar, d, 8); az += __shfl_down(az, d, 8);
                an += __shfl_down(an, d, 8); hr += __shfl_down(hr, d, 8);
                hz += __shfl_down(hz, d, 8); hn += __shfl_down(hn, d, 8);
            }
            if (sub == 0) {
                const float r = fsig(ar + bih1[jj] + hr + bhh1[jj]);
                const float z = fsig(az + bih1[512 + jj] + hz + bhh1[512 + jj]);
                const float n = ftanhf(an + bih1[1024 + jj] + r * (hn + bhh1[1024 + jj]));
                const float hv = (1.f - z) * n + z * hL[jj];
                h1new[b * kH + jj] = hv;
                h1sL[rr] = hv;
            }
            __syncthreads();
            // hid_proj partials for next step: k-slice = this block's 32 h1 values
            for (int jj2 = 0; jj2 < 2; ++jj2) {
                const int j = tid + jj2 * 256;
                float acc = 0.f;
#pragma unroll
                for (int kk = 0; kk < 32; ++kk) acc += h1sL[kk] * WhidT[(g * 32 + kk) * kH + j];
                hidP[(g * kB + b) * kH + j] = acc;
            }
            // out partials (h1 slice term)
            if (tid < kF) {
                float acc = 0.f;
#pragma unroll
                for (int kk = 0; kk < 32; ++kk) acc += h1sL[kk] * outW[tid * 1032 + g * 32 + kk];
                outP[(b * 16 + g) * kF + tid] = acc;
            }
            // out base term (weighted + x_in + bias), by g==0 blocks
            if (g == 0) {
                const int f = tid >> 5, lane = tid & 31;
                float acc = 0.f;
                for (int j = lane; j < kH; j += 32)
                    acc += weiG[b * kH + j] * outW[f * 1032 + 512 + j];
#pragma unroll
                for (int d = 16; d > 0; d >>= 1) acc += __shfl_down(acc, d, 32);
                if (lane == 0) {
#pragma unroll
                    for (int ff = 0; ff < kF; ++ff)
                        acc += xin[b * kF + ff] * outW[f * 1032 + 1024 + ff];
                    outBs[b * kF + f] = acc + outBias[f];
                }
            }
        }
        gbar(cnt, barcount);
    }

    // epilogue: reduce step-31 output
    if (g == 0 && tid < kF) {
        float o = outBs[b * kF + tid];
#pragma unroll
        for (int gg = 0; gg < 16; ++gg) o += outP[(b * 16 + gg) * kF + tid];
        out[b * kT * kF + 31 * kF + tid] = fmaxf(o, 0.f);
    }
}

extern "C" void kernel_launch(void* const* d_in, const int* in_sizes, int n_in,
                              void* d_out, int out_size, void* d_ws, size_t ws_size,
                              hipStream_t stream) {
    (void)in_sizes; (void)n_in; (void)out_size; (void)ws_size;
    hipMemsetAsync(d_ws, 0, 1024, stream);  // zero barrier counter
    decoder_kernel<<<NBLK, NTHR, 0, stream>>>(
        (const float*)d_in[0], (const float*)d_in[1], (const float*)d_in[2],
        (const float*)d_in[3], (const float*)d_in[4], (const float*)d_in[5],
        (const float*)d_in[6], (const float*)d_in[7], (const float*)d_in[8],
        (const float*)d_in[9], (const float*)d_in[10], (const float*)d_in[11],
        (const float*)d_in[12], (const float*)d_in[13], (const float*)d_in[14],
        (const float*)d_in[15], (float*)d_out, (float*)d_ws);
}

// Round 3
// 3093.261 us; speedup vs baseline: 1.3638x; 1.3638x over previous
//
#include <hip/hip_runtime.h>

// DecoderWithAttention: B=16, T=32, F=8, S_ENC=256, H=512, L=2.
// Persistent kernel, fp32. 256 blocks x 256 threads; (b = bid>>4, g = bid&15).
//
// R2 redesign of the memory model:
//  - R1's per-barrier release/acquire fences compiled to buffer_wbl2+buffer_inv
//    => every barrier flushed+invalidated ALL of L2 (FETCH_SIZE 266MB, 127us/step,
//    VALUBusy 5.6%). Fences are gone entirely.
//  - Cross-block communication uses per-access coherent ops: relaxed system-scope
//    atomic load/store (emit sc0 sc1 => bypass L1/L2, hit the coherence point).
//    Read-only weights use plain cached loads and stay L2-resident all run.
//  - Barriers: s_waitcnt(0) to drain write-through stores, relaxed arrive,
//    relaxed poll, workgroup-scope fences for compiler ordering only.
//  - All per-step barriers are 16-block b-group barriers (comm is group-local);
//    only the two prologue barriers are grid-wide.
//  - Same-block round-trips (weighted vec, out base term) live in persistent LDS.

namespace {
constexpr int kB = 16, kT = 32, kF = 8, kS = 256, kH = 512;
constexpr int NBLK = 256, NTHR = 256;

// ws layout (floats). [0..639]: barrier counters (grid at 0, group b at 32*(b+1)).
constexpr int OFF_WENCT = 640;                        // [512][512]  attn_W[:,512:].T
constexpr int OFF_WHIDT = OFF_WENCT + kH * kH;        // [512][512]  attn_W[:,:512].T
constexpr int OFF_ENCP  = OFF_WHIDT + kH * kH;        // [B][S][H]   enc projection + bias
constexpr int OFF_HIDP  = OFF_ENCP + kB * kS * kH;    // [16][B][H]  hid_proj partials
constexpr int OFF_PWP   = OFF_HIDP + 16 * kB * kH;    // [B][16][H]  weighted partials
constexpr int OFF_MP    = OFF_PWP + kB * 16 * kH;     // [B][16]     softmax slice max
constexpr int OFF_LP    = OFF_MP + kB * 16;           // [B][16]     softmax slice expsum
constexpr int OFF_H0    = OFF_LP + kB * 16;           // [2][B][H]   h0 double buffer
constexpr int OFF_H1    = OFF_H0 + 2 * kB * kH;       // [2][B][H]   h1 double buffer
constexpr int OFF_XIN   = OFF_H1 + 2 * kB * kH;       // [B][F]      current x_in
constexpr int OFF_OUTP  = OFF_XIN + kB * kF;          // [B][16][F]  out partials
}  // namespace

__device__ __forceinline__ float fsig(float x) { return 1.0f / (1.0f + __expf(-x)); }
__device__ __forceinline__ float ftanhf(float x) {
    float e = __expf(2.0f * x);
    return 1.0f - 2.0f / (e + 1.0f);
}

// Per-access coherent ops: bypass L1/L2 (sc0 sc1), no fences needed around them.
__device__ __forceinline__ float cload(const float* p) {
    return __hip_atomic_load(p, __ATOMIC_RELAXED, __HIP_MEMORY_SCOPE_SYSTEM);
}
__device__ __forceinline__ void cstore(float* p, float v) {
    __hip_atomic_store(p, v, __ATOMIC_RELAXED, __HIP_MEMORY_SCOPE_SYSTEM);
}

// Barrier with NO cache maintenance: drain stores (they are write-through
// coherent), relaxed arrive, relaxed poll. Workgroup fences = compiler ordering.
__device__ __forceinline__ void bar_sync(unsigned* cnt, unsigned target) {
    __syncthreads();
    if (threadIdx.x == 0) {
        __builtin_amdgcn_fence(__ATOMIC_RELEASE, "workgroup");
        __builtin_amdgcn_s_waitcnt(0);  // all sc1 stores reached coherence point
        __hip_atomic_fetch_add(cnt, 1u, __ATOMIC_RELAXED, __HIP_MEMORY_SCOPE_SYSTEM);
        while (__hip_atomic_load(cnt, __ATOMIC_RELAXED, __HIP_MEMORY_SCOPE_SYSTEM) < target)
            __builtin_amdgcn_s_sleep(2);
        __builtin_amdgcn_fence(__ATOMIC_ACQUIRE, "workgroup");
    }
    __syncthreads();
}

__global__ __launch_bounds__(NTHR) void decoder_kernel(
    const float* __restrict__ target, const float* __restrict__ hidden0,
    const float* __restrict__ enc, const float* __restrict__ attn_W,
    const float* __restrict__ attn_b, const float* __restrict__ v_w,
    const float* __restrict__ Wih0, const float* __restrict__ Whh0,
    const float* __restrict__ bih0, const float* __restrict__ bhh0,
    const float* __restrict__ Wih1, const float* __restrict__ Whh1,
    const float* __restrict__ bih1, const float* __restrict__ bhh1,
    const float* __restrict__ outW, const float* __restrict__ outBias,
    float* __restrict__ out, float* __restrict__ ws) {
    const int tid = threadIdx.x;
    const int bid = blockIdx.x;
    const int b = bid >> 4;
    const int g = bid & 15;
    unsigned* gridCnt = (unsigned*)ws;              // grid barrier counter
    unsigned* grpCnt = (unsigned*)ws + 32 * (b + 1); // this b-group's counter
    unsigned grpBars = 0;

    float* WencT = ws + OFF_WENCT;
    float* WhidT = ws + OFF_WHIDT;
    float* encp  = ws + OFF_ENCP;
    float* hidP  = ws + OFF_HIDP;
    float* pwP   = ws + OFF_PWP;
    float* mP    = ws + OFF_MP;
    float* lP    = ws + OFF_LP;
    float* h0buf = ws + OFF_H0;
    float* h1buf = ws + OFF_H1;
    float* xin   = ws + OFF_XIN;
    float* outP  = ws + OFF_OUTP;

    __shared__ float lds[8192];  // 32 KB
    float* ldsOutB = lds + 1200; // [8]   persistent: out base term (g==0 block)
    float* ldsWei  = lds + 1216; // [512] persistent: weighted vec (g==0 block)

    // ================= P0a: transposes + state init + initial hid_proj partials =====
    {
        for (int kk = 0; kk < 2; ++kk) {
            const int k = bid * 2 + kk;
            for (int jj = 0; jj < 2; ++jj) {
                const int j = tid + jj * 256;
                cstore(&WencT[k * kH + j], attn_W[j * 1024 + 512 + k]);
                cstore(&WhidT[k * kH + j], attn_W[j * 1024 + k]);
            }
        }
        if (g == 0 && tid < kF) cstore(&xin[b * kF + tid], target[b * kT * kF + tid]);
        if (tid < 32) {
            const int j = g * 32 + tid;
            cstore(&h0buf[b * kH + j], hidden0[0 * kB * kH + b * kH + j]);
            cstore(&h1buf[b * kH + j], hidden0[1 * kB * kH + b * kH + j]);
        }
        const float* h1i = hidden0 + kB * kH + b * kH + g * 32;
        for (int jj = 0; jj < 2; ++jj) {
            const int j = tid + jj * 256;
            const float* wrow = attn_W + j * 1024 + g * 32;
            float acc = 0.f;
#pragma unroll
            for (int k = 0; k < 32; ++k) acc += h1i[k] * wrow[k];
            cstore(&hidP[(g * kB + b) * kH + j], acc);
        }
    }
    bar_sync(gridCnt, NBLK);  // grid-wide: transposes feed all blocks

    // ================= P0b: enc_proj = enc @ WencT + attn_b =========================
    {
        const int r0 = bid * 16;  // rows of the 4096 (b,s) rows -> group-local output
        for (int idx = tid; idx < 16 * kH; idx += NTHR) {
            const int r = idx >> 9, k = idx & 511;
            lds[idx] = enc[(r0 + r) * kH + k];
        }
        __syncthreads();
        float acc0[16], acc1[16];
#pragma unroll
        for (int r = 0; r < 16; ++r) { acc0[r] = 0.f; acc1[r] = 0.f; }
        for (int k = 0; k < kH; ++k) {
            const float w0 = cload(&WencT[k * kH + tid]);
            const float w1 = cload(&WencT[k * kH + tid + 256]);
#pragma unroll
            for (int r = 0; r < 16; ++r) {
                const float e = lds[r * kH + k];
                acc0[r] += e * w0;
                acc1[r] += e * w1;
            }
        }
        const float b0 = attn_b[tid], b1 = attn_b[tid + 256];
#pragma unroll
        for (int r = 0; r < 16; ++r) {
            cstore(&encp[(r0 + r) * kH + tid], acc0[r] + b0);
            cstore(&encp[(r0 + r) * kH + tid + 256], acc1[r] + b1);
        }
    }
    bar_sync(grpCnt, 16 * (++grpBars));  // encp rows are group-local

    // ================= main 32-step recurrence ======================================
    float* scoresL = lds + 512;  // [16]
    float* ewL = lds + 528;      // [16]
    for (int t = 0; t < kT; ++t) {
        const int par = t & 1;
        const float* h0old = h0buf + par * kB * kH;
        float* h0new = h0buf + (par ^ 1) * kB * kH;
        const float* h1old = h1buf + par * kB * kH;
        float* h1new = h1buf + (par ^ 1) * kB * kH;

        // ---------- S2: hid_proj reduce + scores + softmax partials ----------
        for (int jj = 0; jj < 2; ++jj) {
            const int j = tid + jj * 256;
            float acc = 0.f;
#pragma unroll
            for (int gg = 0; gg < 16; ++gg) acc += cload(&hidP[(gg * kB + b) * kH + j]);
            lds[j] = acc;
        }
        if (t > 0 && g == 0 && tid < kF) {  // reduce previous step's output
            float o = ldsOutB[tid];
#pragma unroll
            for (int gg = 0; gg < 16; ++gg) o += cload(&outP[(b * 16 + gg) * kF + tid]);
            o = fmaxf(o, 0.f);
            out[b * kT * kF + (t - 1) * kF + tid] = o;
            cstore(&xin[b * kF + tid], o);
        }
        __syncthreads();
        {
            const int sgrp = tid >> 4, lane = tid & 15;
            const int s = g * 16 + sgrp;
            const float* ep = encp + (b * kS + s) * kH;
            float acc = 0.f;
            for (int j = lane; j < kH; j += 16) acc += v_w[j] * ftanhf(ep[j] + lds[j]);
#pragma unroll
            for (int d = 8; d > 0; d >>= 1) acc += __shfl_down(acc, d, 16);
            if (lane == 0) scoresL[sgrp] = acc;
        }
        __syncthreads();
        {
            float m = -1e30f;
#pragma unroll
            for (int i = 0; i < 16; ++i) m = fmaxf(m, scoresL[i]);
            float l = 0.f;
#pragma unroll
            for (int i = 0; i < 16; ++i) l += __expf(scoresL[i] - m);
            if (tid < 16) ewL[tid] = __expf(scoresL[tid] - m);
            if (tid == 0) { cstore(&mP[b * 16 + g], m); cstore(&lP[b * 16 + g], l); }
        }
        __syncthreads();
        for (int jj = 0; jj < 2; ++jj) {
            const int j = tid + jj * 256;
            float acc = 0.f;
#pragma unroll
            for (int i = 0; i < 16; ++i) acc += ewL[i] * enc[(b * kS + g * 16 + i) * kH + j];
            cstore(&pwP[(b * 16 + g) * kH + j], acc);
        }
        bar_sync(grpCnt, 16 * (++grpBars));

        // ---------- S3: weighted combine + GRU layer 0 ----------
        {
            float c[16], mv[16], lv[16];
#pragma unroll
            for (int gg = 0; gg < 16; ++gg) {
                mv[gg] = cload(&mP[b * 16 + gg]);
                lv[gg] = cload(&lP[b * 16 + gg]);
            }
            float M = -1e30f;
#pragma unroll
            for (int gg = 0; gg < 16; ++gg) M = fmaxf(M, mv[gg]);
            float denom = 0.f;
#pragma unroll
            for (int gg = 0; gg < 16; ++gg) {
                c[gg] = __expf(mv[gg] - M);
                denom += lv[gg] * c[gg];
            }
            const float inv = 1.f / denom;
#pragma unroll
            for (int gg = 0; gg < 16; ++gg) c[gg] *= inv;
            float* xL = lds;         // [520]: x = [x_in, weighted]
            float* hL = lds + 576;   // [512]: h0_old
            for (int jj = 0; jj < 2; ++jj) {
                const int j = tid + jj * 256;
                float acc = 0.f;
#pragma unroll
                for (int gg = 0; gg < 16; ++gg) acc += c[gg] * cload(&pwP[(b * 16 + gg) * kH + j]);
                xL[kF + j] = acc;
                if (g == 0) ldsWei[j] = acc;
                hL[j] = cload(&h0old[b * kH + j]);
            }
            if (tid < kF) xL[tid] = cload(&xin[b * kF + tid]);
            __syncthreads();
            const int rr = tid >> 3, sub = tid & 7;
            const int jj = g * 32 + rr;
            const float* wr = Wih0 + jj * 520;
            const float* wz = Wih0 + (512 + jj) * 520;
            const float* wn = Wih0 + (1024 + jj) * 520;
            float ar = 0.f, az = 0.f, an = 0.f;
            for (int k = sub; k < 520; k += 8) {
                const float xv = xL[k];
                ar += xv * wr[k]; az += xv * wz[k]; an += xv * wn[k];
            }
            const float* ur = Whh0 + jj * kH;
            const float* uz = Whh0 + (512 + jj) * kH;
            const float* un = Whh0 + (1024 + jj) * kH;
            float hr = 0.f, hz = 0.f, hn = 0.f;
            for (int k = sub; k < kH; k += 8) {
                const float hv = hL[k];
                hr += hv * ur[k]; hz += hv * uz[k]; hn += hv * un[k];
            }
#pragma unroll
            for (int d = 4; d > 0; d >>= 1) {
                ar += __shfl_down(ar, d, 8); az += __shfl_down(az, d, 8);
                an += __shfl_down(an, d, 8); hr += __shfl_down(hr, d, 8);
                hz += __shfl_down(hz, d, 8); hn += __shfl_down(hn, d, 8);
            }
            if (sub == 0) {
                const float r = fsig(ar + bih0[jj] + hr + bhh0[jj]);
                const float z = fsig(az + bih0[512 + jj] + hz + bhh0[512 + jj]);
                const float n = ftanhf(an + bih0[1024 + jj] + r * (hn + bhh0[1024 + jj]));
                cstore(&h0new[b * kH + jj], (1.f - z) * n + z * hL[jj]);
            }
        }
        bar_sync(grpCnt, 16 * (++grpBars));

        // ---------- S4: GRU layer 1 + next hid_proj partials + out partials ----------
        {
            float* xL = lds;          // [512]: h0_new
            float* hL = lds + 576;    // [512]: h1_old
            float* h1sL = lds + 1152; // [32]:  this block's h1_new slice
            for (int jj = 0; jj < 2; ++jj) {
                const int j = tid + jj * 256;
                xL[j] = cload(&h0new[b * kH + j]);
                hL[j] = cload(&h1old[b * kH + j]);
            }
            __syncthreads();
            const int rr = tid >> 3, sub = tid & 7;
            const int jj = g * 32 + rr;
            const float* wr = Wih1 + jj * kH;
            const float* wz = Wih1 + (512 + jj) * kH;
            const float* wn = Wih1 + (1024 + jj) * kH;
            const float* ur = Whh1 + jj * kH;
            const float* uz = Whh1 + (512 + jj) * kH;
            const float* un = Whh1 + (1024 + jj) * kH;
            float ar = 0.f, az = 0.f, an = 0.f, hr = 0.f, hz = 0.f, hn = 0.f;
            for (int k = sub; k < kH; k += 8) {
                const float xv = xL[k], hv = hL[k];
                ar += xv * wr[k]; az += xv * wz[k]; an += xv * wn[k];
                hr += hv * ur[k]; hz += hv * uz[k]; hn += hv * un[k];
            }
#pragma unroll
            for (int d = 4; d > 0; d >>= 1) {
                ar += __shfl_down(ar, d, 8); az += __shfl_down(az, d, 8);
                an += __shfl_down(an, d, 8); hr += __shfl_down(hr, d, 8);
                hz += __shfl_down(hz, d, 8); hn += __shfl_down(hn, d, 8);
            }
            if (sub == 0) {
                const float r = fsig(ar + bih1[jj] + hr + bhh1[jj]);
                const float z = fsig(az + bih1[512 + jj] + hz + bhh1[512 + jj]);
                const float n = ftanhf(an + bih1[1024 + jj] + r * (hn + bhh1[1024 + jj]));
                const float hv = (1.f - z) * n + z * hL[jj];
                cstore(&h1new[b * kH + jj], hv);
                h1sL[rr] = hv;
            }
            __syncthreads();
            for (int jj2 = 0; jj2 < 2; ++jj2) {
                const int j = tid + jj2 * 256;
                float acc = 0.f;
#pragma unroll
                for (int kk = 0; kk < 32; ++kk) acc += h1sL[kk] * cload(&WhidT[(g * 32 + kk) * kH + j]);
                cstore(&hidP[(g * kB + b) * kH + j], acc);
            }
            if (tid < kF) {
                float acc = 0.f;
#pragma unroll
                for (int kk = 0; kk < 32; ++kk) acc += h1sL[kk] * outW[tid * 1032 + g * 32 + kk];
                cstore(&outP[(b * 16 + g) * kF + tid], acc);
            }
            if (g == 0) {
                const int f = tid >> 5, lane = tid & 31;
                float acc = 0.f;
                for (int j = lane; j < kH; j += 32)
                    acc += ldsWei[j] * outW[f * 1032 + 512 + j];
#pragma unroll
                for (int d = 16; d > 0; d >>= 1) acc += __shfl_down(acc, d, 32);
                if (lane == 0) {
                    float xacc = acc;
#pragma unroll
                    for (int ff = 0; ff < kF; ++ff)
                        xacc += cload(&xin[b * kF + ff]) * outW[f * 1032 + 1024 + ff];
                    ldsOutB[f] = xacc + outBias[f];
                }
            }
        }
        bar_sync(grpCnt, 16 * (++grpBars));
    }

    // epilogue: reduce step-31 output
    if (g == 0 && tid < kF) {
        float o = ldsOutB[tid];
#pragma unroll
        for (int gg = 0; gg < 16; ++gg) o += cload(&outP[(b * 16 + gg) * kF + tid]);
        out[b * kT * kF + 31 * kF + tid] = fmaxf(o, 0.f);
    }
}

extern "C" void kernel_launch(void* const* d_in, const int* in_sizes, int n_in,
                              void* d_out, int out_size, void* d_ws, size_t ws_size,
                              hipStream_t stream) {
    (void)in_sizes; (void)n_in; (void)out_size; (void)ws_size;
    hipMemsetAsync(d_ws, 0, 4096, stream);  // zero barrier counters
    decoder_kernel<<<NBLK, NTHR, 0, stream>>>(
        (const float*)d_in[0], (const float*)d_in[1], (const float*)d_in[2],
        (const float*)d_in[3], (const float*)d_in[4], (const float*)d_in[5],
        (const float*)d_in[6], (const float*)d_in[7], (const float*)d_in[8],
        (const float*)d_in[9], (const float*)d_in[10], (const float*)d_in[11],
        (const float*)d_in[12], (const float*)d_in[13], (const float*)d_in[14],
        (const float*)d_in[15], (float*)d_out, (float*)d_ws);
}

// Round 4
// 2381.480 us; speedup vs baseline: 1.7714x; 1.2989x over previous
//
#include <hip/hip_runtime.h>

// DecoderWithAttention: B=16, T=32, F=8, S_ENC=256, H=512, L=2.
// R3: (b,q) decomposition. 128 wg x 256 thr; b = batch group (16), q = row/s
// slice (8). All matvecs row-sliced (weights read once/step, L2-resident).
// Cross-block traffic = small activation vectors via uncached (sc0 sc1)
// atomics; weights/enc/encp via plain cached loads. f16 packed weights +
// v_dot2_f32_f16 (fp32 accumulate). 4 group barriers (8 blocks) per step.
// Softmax without max-pass (|score| <= ~20, exp is fp32-safe; shift-invariant).

namespace {
constexpr int kB = 16, kT = 32, kF = 8, kS = 256, kH = 512;
constexpr int NBLK = 128, NTHR = 256;

// ws layout in float units.
// [0..511]: per-b group counters (32-float spacing); [512]: grid counter.
constexpr int OFF_AEH   = 1024;     // [512 j][256] u32 pairs: attn_W[:,512:] f16
constexpr int OFF_WHID  = 263168 - 131072;            // = 132096 [512][256]
constexpr int OFF_WIH0  = 263168;   // [1536][260]
constexpr int OFF_WHH0  = 662528;   // [1536][256]
constexpr int OFF_WIH1  = 1055744;  // [1536][256]
constexpr int OFF_WHH1  = 1448960;  // [1536][256]
constexpr int OFF_ENCH  = 1842176;  // [4096][256]  enc f16 pairs
constexpr int OFF_ENCP  = 2890752;  // [4096][256]  enc_proj f16 pairs
constexpr int OFF_HIDP  = 3939328;  // [16][512] fp32
constexpr int OFF_WPART = 3947520;  // [16][8][512] fp32
constexpr int OFF_LPART = 4013056;  // [16][8]
constexpr int OFF_H0    = 4013184;  // [2][16][512]
constexpr int OFF_H1    = 4029568;  // [2][16][512]
constexpr int OFF_XIN   = 4045952;  // [16][8]
constexpr int OFF_OUTP  = 4046080;  // [16][8][8]
constexpr int OFF_OUTB  = 4047104;  // [16][8]
}  // namespace

typedef _Float16 h2 __attribute__((ext_vector_type(2)));
union U32H { unsigned u; h2 h; };

__device__ __forceinline__ float dot2(unsigned a, unsigned b, float acc) {
    U32H ua, ub; ua.u = a; ub.u = b;
#if __has_builtin(__builtin_amdgcn_fdot2)
    return __builtin_amdgcn_fdot2(ua.h, ub.h, acc, false);
#else
    return acc + (float)ua.h.x * (float)ub.h.x + (float)ua.h.y * (float)ub.h.y;
#endif
}
__device__ __forceinline__ unsigned packh2(float a, float b) {
    U32H u; u.h = h2{(_Float16)a, (_Float16)b}; return u.u;
}
__device__ __forceinline__ float fsig(float x) { return 1.0f / (1.0f + __expf(-x)); }
__device__ __forceinline__ float ftanhf(float x) {
    float e = __expf(2.0f * x);
    return 1.0f - 2.0f / (e + 1.0f);
}
__device__ __forceinline__ float cload(const float* p) {
    return __hip_atomic_load(p, __ATOMIC_RELAXED, __HIP_MEMORY_SCOPE_SYSTEM);
}
__device__ __forceinline__ void cstore(float* p, float v) {
    __hip_atomic_store(p, v, __ATOMIC_RELAXED, __HIP_MEMORY_SCOPE_SYSTEM);
}
__device__ __forceinline__ void ucstore(unsigned* p, unsigned v) {
    __hip_atomic_store(p, v, __ATOMIC_RELAXED, __HIP_MEMORY_SCOPE_SYSTEM);
}

// Barrier w/o cache maintenance (same structure as R2 which validated clean):
// __syncthreads drains each wave's vmem stores; relaxed arrive+poll.
__device__ __forceinline__ void bar_sync(unsigned* cnt, unsigned target) {
    __syncthreads();
    if (threadIdx.x == 0) {
        __builtin_amdgcn_fence(__ATOMIC_RELEASE, "workgroup");
        __builtin_amdgcn_s_waitcnt(0);
        __hip_atomic_fetch_add(cnt, 1u, __ATOMIC_RELAXED, __HIP_MEMORY_SCOPE_SYSTEM);
        while (__hip_atomic_load(cnt, __ATOMIC_RELAXED, __HIP_MEMORY_SCOPE_SYSTEM) < target)
            __builtin_amdgcn_s_sleep(2);
        __builtin_amdgcn_fence(__ATOMIC_ACQUIRE, "workgroup");
    }
    __syncthreads();
}

__global__ __launch_bounds__(NTHR) void decoder_kernel(
    const float* __restrict__ target, const float* __restrict__ hidden0,
    const float* __restrict__ enc, const float* __restrict__ attn_W,
    const float* __restrict__ attn_b, const float* __restrict__ v_w,
    const float* __restrict__ Wih0, const float* __restrict__ Whh0,
    const float* __restrict__ bih0, const float* __restrict__ bhh0,
    const float* __restrict__ Wih1, const float* __restrict__ Whh1,
    const float* __restrict__ bih1, const float* __restrict__ bhh1,
    const float* __restrict__ outW, const float* __restrict__ outBias,
    float* __restrict__ out, float* __restrict__ ws) {
    const int tid = threadIdx.x;
    const int bid = blockIdx.x;
    // bid = (b&7) + 8*(q + 8*(b>>3)): same-b group shares bid%8 (same XCD
    // under round-robin dispatch -> group barrier likely intra-XCD).
    const int b = (bid & 7) | ((bid >> 6) << 3);
    const int q = (bid >> 3) & 7;
    unsigned* grpCnt = (unsigned*)ws + 32 * b;
    unsigned* gridCnt = (unsigned*)ws + 512;
    unsigned bars = 0;

    unsigned* aehU  = (unsigned*)(ws + OFF_AEH);
    unsigned* whidU = (unsigned*)(ws + OFF_WHID);
    unsigned* wih0U = (unsigned*)(ws + OFF_WIH0);
    unsigned* whh0U = (unsigned*)(ws + OFF_WHH0);
    unsigned* wih1U = (unsigned*)(ws + OFF_WIH1);
    unsigned* whh1U = (unsigned*)(ws + OFF_WHH1);
    unsigned* encU  = (unsigned*)(ws + OFF_ENCH);
    unsigned* encpU = (unsigned*)(ws + OFF_ENCP);
    float* hidP  = ws + OFF_HIDP;
    float* wpart = ws + OFF_WPART;
    float* lpart = ws + OFF_LPART;
    float* h0buf = ws + OFF_H0;
    float* h1buf = ws + OFF_H1;
    float* xin   = ws + OFF_XIN;
    float* outP  = ws + OFF_OUTP;
    float* outBs = ws + OFF_OUTB;

    __shared__ float lds[2600];
    float* F0 = lds;                        // [512] fp32 vector
    float* F1 = lds + 512;                  // [512] fp32 vector
    unsigned* U0 = (unsigned*)(lds + 1024); // [260] f16 pairs
    unsigned* U1 = (unsigned*)(lds + 1536); // [256] f16 pairs
    float* AX = lds + 2048;                 // [192] x-side gate pre-acts
    float* AH = lds + 2240;                 // [192] h-side gate pre-acts
    float* ES = lds + 2432;                 // [32]  exp(scores)
    float* H1S = lds + 2464;                // [64]  h1 slice
    float* XINL = lds + 2528;               // [8]

    const int gtid = bid * NTHR + tid;  // 0..32767

    // ===================== P1: f16 conversion + state init =====================
    for (int i = gtid; i < 512 * 256; i += NBLK * NTHR) {
        const int j = i >> 8, p = i & 255;
        ucstore(&aehU[i], packh2(attn_W[j * 1024 + 512 + 2 * p], attn_W[j * 1024 + 513 + 2 * p]));
        ucstore(&whidU[i], packh2(attn_W[j * 1024 + 2 * p], attn_W[j * 1024 + 1 + 2 * p]));
    }
    for (int i = gtid; i < 1536 * 260; i += NBLK * NTHR)
        ucstore(&wih0U[i], packh2(Wih0[2 * i], Wih0[2 * i + 1]));
    for (int i = gtid; i < 1536 * 256; i += NBLK * NTHR) {
        ucstore(&whh0U[i], packh2(Whh0[2 * i], Whh0[2 * i + 1]));
        ucstore(&wih1U[i], packh2(Wih1[2 * i], Wih1[2 * i + 1]));
        ucstore(&whh1U[i], packh2(Whh1[2 * i], Whh1[2 * i + 1]));
    }
    for (int i = gtid; i < 4096 * 256; i += NBLK * NTHR)
        ucstore(&encU[i], packh2(enc[2 * i], enc[2 * i + 1]));
    for (int i = gtid; i < kB * kH; i += NBLK * NTHR) {
        cstore(&h0buf[i], hidden0[i]);
        cstore(&h1buf[i], hidden0[kB * kH + i]);
    }
    if (gtid < kB * kF) {
        const int bb = gtid >> 3, f = gtid & 7;
        cstore(&xin[gtid], target[bb * kT * kF + f]);
    }
    bar_sync(gridCnt, NBLK);

    // ===================== P2: enc_proj (own slice) in f16 =====================
    {
        const int r0 = b * kS + q * 32;
        const int j0 = 2 * tid, j1 = 2 * tid + 1;
        const unsigned* w0 = &aehU[j0 * 256];
        const unsigned* w1 = &aehU[j1 * 256];
        const float bb0 = attn_b[j0], bb1 = attn_b[j1];
        for (int rloc = 0; rloc < 32; ++rloc) {
            const unsigned* erow = &encU[(r0 + rloc) * 256];
            float a0 = bb0, a1 = bb1;
            for (int p = 0; p < 256; ++p) {
                const unsigned e = erow[p];
                a0 = dot2(e, w0[p], a0);
                a1 = dot2(e, w1[p], a1);
            }
            encpU[(r0 + rloc) * 256 + tid] = packh2(a0, a1);  // self-read only
        }
    }

    // ===================== main recurrence: A -> B -> CD -> E ==================
    for (int t = 0; t < kT; ++t) {
        const int par = t & 1;
        const float* h0old = h0buf + par * kB * kH + b * kH;
        float* h0new = h0buf + (par ^ 1) * kB * kH + b * kH;
        const float* h1old = h1buf + par * kB * kH + b * kH;
        float* h1new = h1buf + (par ^ 1) * kB * kH + b * kH;

        // ---- A: previous-step out reduce -> xin; hidp j-slice ----
        {
            if (t > 0 && tid < kF) {
                float o = cload(&outBs[b * kF + tid]);
#pragma unroll
                for (int q2 = 0; q2 < 8; ++q2) o += cload(&outP[(b * 8 + q2) * kF + tid]);
                o = fmaxf(o, 0.f);
                out[b * kT * kF + (t - 1) * kF + tid] = o;
                cstore(&xin[b * kF + tid], o);
            }
            F0[tid] = cload(&h1old[tid]);
            F0[tid + 256] = cload(&h1old[tid + 256]);
            __syncthreads();
            U0[tid] = packh2(F0[2 * tid], F0[2 * tid + 1]);
            __syncthreads();
            const int rloc = tid >> 2, sub = tid & 3;
            const int row = q * 64 + rloc;
            const unsigned* wrow = &whidU[row * 256 + sub * 64];
            float acc = 0.f;
#pragma unroll 16
            for (int k = 0; k < 64; ++k) acc = dot2(U0[sub * 64 + k], wrow[k], acc);
            acc += __shfl_down(acc, 1, 4);
            acc += __shfl_down(acc, 2, 4);
            if (sub == 0) cstore(&hidP[b * kH + row], acc);
        }
        bar_sync(grpCnt, 8 * (++bars));

        // ---- B: energy (s-slice) + exp + partial weighted ----
        {
            F0[tid] = cload(&hidP[b * kH + tid]);
            F0[tid + 256] = cload(&hidP[b * kH + tid + 256]);
            __syncthreads();
            const int sloc = tid >> 3, sub = tid & 7;
            const unsigned* eprow = &encpU[(b * kS + q * 32 + sloc) * 256];
            float acc = 0.f;
            for (int k = 0; k < 32; ++k) {
                const int p = sub * 32 + k;
                U32H u; u.u = eprow[p];
                const int j = 2 * p;
                acc += v_w[j] * ftanhf((float)u.h.x + F0[j]);
                acc += v_w[j + 1] * ftanhf((float)u.h.y + F0[j + 1]);
            }
            acc += __shfl_down(acc, 1, 8);
            acc += __shfl_down(acc, 2, 8);
            acc += __shfl_down(acc, 4, 8);
            if (sub == 0) ES[sloc] = __expf(acc);  // no max-shift: |score|<=~20
            __syncthreads();
            float wp0 = 0.f, wp1 = 0.f;
            const unsigned* erow = &encU[(b * kS + q * 32) * 256 + tid];
            for (int sloc2 = 0; sloc2 < 32; ++sloc2) {
                U32H u; u.u = erow[sloc2 * 256];
                const float es = ES[sloc2];
                wp0 += es * (float)u.h.x;
                wp1 += es * (float)u.h.y;
            }
            cstore(&wpart[(b * 8 + q) * kH + 2 * tid], wp0);
            cstore(&wpart[(b * 8 + q) * kH + 2 * tid + 1], wp1);
            if (tid == 0) {
                float l = 0.f;
#pragma unroll
                for (int i = 0; i < 32; ++i) l += ES[i];
                cstore(&lpart[b * 8 + q], l);
            }
        }
        bar_sync(grpCnt, 8 * (++bars));

        // ---- CD: reduce weighted (redundant) + GRU0 row-slice + out base ----
        {
            float L = 0.f;
#pragma unroll
            for (int q2 = 0; q2 < 8; ++q2) L += cload(&lpart[b * 8 + q2]);
            const float inv = 1.f / L;
            float w0 = 0.f, w1 = 0.f;
#pragma unroll
            for (int q2 = 0; q2 < 8; ++q2) {
                w0 += cload(&wpart[(b * 8 + q2) * kH + 2 * tid]);
                w1 += cload(&wpart[(b * 8 + q2) * kH + 2 * tid + 1]);
            }
            w0 *= inv; w1 *= inv;
            F1[2 * tid] = w0; F1[2 * tid + 1] = w1;   // weighted fp32
            U0[4 + tid] = packh2(w0, w1);             // x pairs (offset: xin=4 pairs)
            if (tid < kF) XINL[tid] = cload(&xin[b * kF + tid]);
            F0[tid] = cload(&h0old[tid]);
            F0[tid + 256] = cload(&h0old[tid + 256]);
            __syncthreads();
            if (tid < 4) U0[tid] = packh2(XINL[2 * tid], XINL[2 * tid + 1]);
            U1[tid] = packh2(F0[2 * tid], F0[2 * tid + 1]);
            __syncthreads();
            const int gate = tid >> 6, rloc = tid & 63;
            if (gate < 3) {
                const int row = gate * kH + q * 64 + rloc;
                const unsigned* wx = &wih0U[row * 260];
                float xacc = bih0[row];
#pragma unroll 10
                for (int p = 0; p < 260; ++p) xacc = dot2(U0[p], wx[p], xacc);
                const unsigned* wh = &whh0U[row * 256];
                float hacc = bhh0[row];
#pragma unroll 16
                for (int p = 0; p < 256; ++p) hacc = dot2(U1[p], wh[p], hacc);
                AX[tid] = xacc; AH[tid] = hacc;
            } else if (q == 0) {
                // out base: weighted & xin terms (f = 0..7, 8 lanes each)
                const int f = (tid - 192) >> 3, sub = tid & 7;
                float acc = 0.f;
                const float* wrow = &outW[f * 1032 + 512 + sub * 64];
                for (int j = 0; j < 64; ++j) acc += wrow[j] * F1[sub * 64 + j];
                acc += __shfl_down(acc, 1, 8);
                acc += __shfl_down(acc, 2, 8);
                acc += __shfl_down(acc, 4, 8);
                if (sub == 0) {
#pragma unroll
                    for (int ff = 0; ff < kF; ++ff)
                        acc += outW[f * 1032 + 1024 + ff] * XINL[ff];
                    cstore(&outBs[b * kF + f], acc + outBias[f]);
                }
            }
            __syncthreads();
            if (tid < 64) {
                const int jj = q * 64 + tid;
                const float r = fsig(AX[tid] + AH[tid]);
                const float z = fsig(AX[64 + tid] + AH[64 + tid]);
                const float n = ftanhf(AX[128 + tid] + r * AH[128 + tid]);
                cstore(&h0new[jj], (1.f - z) * n + z * F0[jj]);
            }
        }
        bar_sync(grpCnt, 8 * (++bars));

        // ---- E: GRU1 row-slice + h1 slice out-partials ----
        {
            F0[tid] = cload(&h0new[tid]);
            F0[tid + 256] = cload(&h0new[tid + 256]);
            F1[tid] = cload(&h1old[tid]);
            F1[tid + 256] = cload(&h1old[tid + 256]);
            __syncthreads();
            U0[tid] = packh2(F0[2 * tid], F0[2 * tid + 1]);
            U1[tid] = packh2(F1[2 * tid], F1[2 * tid + 1]);
            __syncthreads();
            const int gate = tid >> 6, rloc = tid & 63;
            if (gate < 3) {
                const int row = gate * kH + q * 64 + rloc;
                const unsigned* wx = &wih1U[row * 256];
                float xacc = bih1[row];
#pragma unroll 16
                for (int p = 0; p < 256; ++p) xacc = dot2(U0[p], wx[p], xacc);
                const unsigned* wh = &whh1U[row * 256];
                float hacc = bhh1[row];
#pragma unroll 16
                for (int p = 0; p < 256; ++p) hacc = dot2(U1[p], wh[p], hacc);
                AX[tid] = xacc; AH[tid] = hacc;
            }
            __syncthreads();
            if (tid < 64) {
                const int jj = q * 64 + tid;
                const float r = fsig(AX[tid] + AH[tid]);
                const float z = fsig(AX[64 + tid] + AH[64 + tid]);
                const float n = ftanhf(AX[128 + tid] + r * AH[128 + tid]);
                const float hv = (1.f - z) * n + z * F1[jj];
                cstore(&h1new[jj], hv);
                H1S[tid] = hv;
            }
            __syncthreads();
            if (tid < kF) {
                float acc = 0.f;
                const float* wrow = &outW[tid * 1032 + q * 64];
#pragma unroll
                for (int k = 0; k < 64; ++k) acc += wrow[k] * H1S[k];
                cstore(&outP[(b * 8 + q) * kF + tid], acc);
            }
        }
        bar_sync(grpCnt, 8 * (++bars));
    }

    // epilogue: step-31 output
    if (q == 0 && tid < kF) {
        float o = cload(&outBs[b * kF + tid]);
#pragma unroll
        for (int q2 = 0; q2 < 8; ++q2) o += cload(&outP[(b * 8 + q2) * kF + tid]);
        out[b * kT * kF + 31 * kF + tid] = fmaxf(o, 0.f);
    }
}

extern "C" void kernel_launch(void* const* d_in, const int* in_sizes, int n_in,
                              void* d_out, int out_size, void* d_ws, size_t ws_size,
                              hipStream_t stream) {
    (void)in_sizes; (void)n_in; (void)out_size; (void)ws_size;
    hipMemsetAsync(d_ws, 0, 4096, stream);  // zero barrier counters
    decoder_kernel<<<NBLK, NTHR, 0, stream>>>(
        (const float*)d_in[0], (const float*)d_in[1], (const float*)d_in[2],
        (const float*)d_in[3], (const float*)d_in[4], (const float*)d_in[5],
        (const float*)d_in[6], (const float*)d_in[7], (const float*)d_in[8],
        (const float*)d_in[9], (const float*)d_in[10], (const float*)d_in[11],
        (const float*)d_in[12], (const float*)d_in[13], (const float*)d_in[14],
        (const float*)d_in[15], (float*)d_out, (float*)d_ws);
}

// Round 5
// 1550.444 us; speedup vs baseline: 2.7208x; 1.5360x over previous
//
#include <hip/hip_runtime.h>

// DecoderWithAttention: B=16, T=32, F=8, S_ENC=256, H=512, L=2.
// R5: partition = 2 halves (8 b each) x 128 row-slices j. Block j owns GRU
// h-rows [4j,4j+4) (x3 gates), whid rows [4j,4j+4), attention (b_att=j>>4,
// s in 16*(j&15)..+16) -- computed for its half's 8 batch elements.
// Per-XCD recurring weight footprint ~1.9MB (L2-resident; R4's partition put
// the full 16MB on every XCD -> 1.03GB refetch/dispatch). Activations staged
// to LDS (stride 264: conflict-padded, 16B-aligned) and consumed via uint4
// ds_read + v_dot2_f32_f16. Comm = uncached (sc0 sc1) relaxed atomics only.
// 5 per-half barriers/step. h-state packed f16 across steps.

namespace {
constexpr int kB = 16, kT = 32, kF = 8, kS = 256, kH = 512;
constexpr int NBLK = 256, NTHR = 256;

// ws layout (float units). [0..1023]: counters (half0@0, half1@32, grid@64).
constexpr int OFF_AEH   = 1024;     // [512][256] u32: attn_W[:,512:] f16 pairs
constexpr int OFF_WHID  = 132096;   // [512][256] u32: attn_W[:,:512]
constexpr int OFF_WIH0  = 263168;   // [1536][260] u32
constexpr int OFF_WHH0  = 662528;   // [1536][256] u32
constexpr int OFF_WIH1  = 1055744;  // [1536][256] u32
constexpr int OFF_WHH1  = 1448960;  // [1536][256] u32
constexpr int OFF_ENCH  = 1842176;  // [4096][256] u32: enc f16 pairs
constexpr int OFF_ENCP  = 2890752;  // [4096][256] u32: enc_proj f16 pairs
constexpr int OFF_HIDP  = 3939328;  // [16][512] f32
constexpr int OFF_WPART = 3947520;  // [16][16][512] f32
constexpr int OFF_LPART = 4078592;  // [16][16] f32
constexpr int OFF_WEIC  = 4078848;  // [2][16][256] u32 (parity)
constexpr int OFF_H0C   = 4087040;  // [2][16][256] u32
constexpr int OFF_H1C   = 4095232;  // [2][16][256] u32
constexpr int OFF_XINC  = 4103424;  // [2][16][8] f32
constexpr int OFF_OUTP  = 4103680;  // [16][128][8] f32
}  // namespace

typedef _Float16 h2 __attribute__((ext_vector_type(2)));
union U32H { unsigned u; h2 h; };

__device__ __forceinline__ float dot2(unsigned a, unsigned b, float acc) {
    U32H ua, ub; ua.u = a; ub.u = b;
#if __has_builtin(__builtin_amdgcn_fdot2)
    return __builtin_amdgcn_fdot2(ua.h, ub.h, acc, false);
#else
    return acc + (float)ua.h.x * (float)ub.h.x + (float)ua.h.y * (float)ub.h.y;
#endif
}
__device__ __forceinline__ unsigned packh2(float a, float b) {
    U32H u; u.h = h2{(_Float16)a, (_Float16)b}; return u.u;
}
__device__ __forceinline__ float fsig(float x) { return 1.0f / (1.0f + __expf(-x)); }
__device__ __forceinline__ float ftanhf(float x) {
    float e = __expf(2.0f * x);
    return 1.0f - 2.0f / (e + 1.0f);
}
// Uncached (sc0 sc1 -> coherence point) per-access ops for cross-block comm.
__device__ __forceinline__ float cload(const float* p) {
    return __hip_atomic_load(p, __ATOMIC_RELAXED, __HIP_MEMORY_SCOPE_SYSTEM);
}
__device__ __forceinline__ void cstore(float* p, float v) {
    __hip_atomic_store(p, v, __ATOMIC_RELAXED, __HIP_MEMORY_SCOPE_SYSTEM);
}
__device__ __forceinline__ unsigned ucload(const unsigned* p) {
    return __hip_atomic_load(p, __ATOMIC_RELAXED, __HIP_MEMORY_SCOPE_SYSTEM);
}
__device__ __forceinline__ void ucstore(unsigned* p, unsigned v) {
    __hip_atomic_store(p, v, __ATOMIC_RELAXED, __HIP_MEMORY_SCOPE_SYSTEM);
}

// No-cache-maintenance barrier (validated R2/R4): compiler emits full
// s_waitcnt before s_barrier, so all waves' comm stores are drained before
// thread0 arrives. Relaxed arrive + relaxed poll, workgroup fences only.
__device__ __forceinline__ void bar_sync(unsigned* cnt, unsigned target) {
    __syncthreads();
    if (threadIdx.x == 0) {
        __builtin_amdgcn_fence(__ATOMIC_RELEASE, "workgroup");
        __builtin_amdgcn_s_waitcnt(0);
        __hip_atomic_fetch_add(cnt, 1u, __ATOMIC_RELAXED, __HIP_MEMORY_SCOPE_SYSTEM);
        while (__hip_atomic_load(cnt, __ATOMIC_RELAXED, __HIP_MEMORY_SCOPE_SYSTEM) < target)
            __builtin_amdgcn_s_sleep(2);
        __builtin_amdgcn_fence(__ATOMIC_ACQUIRE, "workgroup");
    }
    __syncthreads();
}

__global__ __launch_bounds__(NTHR) void decoder_kernel(
    const float* __restrict__ target, const float* __restrict__ hidden0,
    const float* __restrict__ enc, const float* __restrict__ attn_W,
    const float* __restrict__ attn_b, const float* __restrict__ v_w,
    const float* __restrict__ Wih0, const float* __restrict__ Whh0,
    const float* __restrict__ bih0, const float* __restrict__ bhh0,
    const float* __restrict__ Wih1, const float* __restrict__ Whh1,
    const float* __restrict__ bih1, const float* __restrict__ bhh1,
    const float* __restrict__ outW, const float* __restrict__ outBias,
    float* __restrict__ out, float* __restrict__ ws) {
    const int tid = threadIdx.x, bid = blockIdx.x;
    const int half = bid >> 7, j = bid & 127;
    const int bloc = j >> 4, sgrp = j & 15;
    const int b_att = half * 8 + bloc;
    unsigned* halfCnt = (unsigned*)ws + 32 * half;
    unsigned* gridCnt = (unsigned*)ws + 64;
    unsigned bars = 0;

    unsigned* aehU  = (unsigned*)(ws + OFF_AEH);
    unsigned* whidU = (unsigned*)(ws + OFF_WHID);
    unsigned* wih0U = (unsigned*)(ws + OFF_WIH0);
    unsigned* whh0U = (unsigned*)(ws + OFF_WHH0);
    unsigned* wih1U = (unsigned*)(ws + OFF_WIH1);
    unsigned* whh1U = (unsigned*)(ws + OFF_WHH1);
    unsigned* encU  = (unsigned*)(ws + OFF_ENCH);
    unsigned* encpU = (unsigned*)(ws + OFF_ENCP);
    float* hidP  = ws + OFF_HIDP;
    float* wpart = ws + OFF_WPART;
    float* lpart = ws + OFF_LPART;
    unsigned* weiCU = (unsigned*)(ws + OFF_WEIC);
    unsigned* h0cU  = (unsigned*)(ws + OFF_H0C);
    unsigned* h1cU  = (unsigned*)(ws + OFF_H1C);
    float* xinC = ws + OFF_XINC;
    float* outP = ws + OFF_OUTP;

    __shared__ __align__(16) float lds[7104];
    unsigned* ldsU = (unsigned*)lds;
    constexpr int L_H1 = 0, L_HX = 2112, L_H0 = 4224, L_VW = 6336,
                  L_HIDP = 2112, L_ES = 6848, L_LP = 6864, L_AX = 6880,
                  L_AH = 6976, L_HS = 7072;
    const int gtid = bid * NTHR + tid;

    // ===================== P1: f16 pack + state init ==========================
    for (int i = gtid; i < 131072; i += NBLK * NTHR) {
        const int jr = i >> 8, p = i & 255;
        ucstore(&aehU[i], packh2(attn_W[jr * 1024 + 512 + 2 * p], attn_W[jr * 1024 + 513 + 2 * p]));
        ucstore(&whidU[i], packh2(attn_W[jr * 1024 + 2 * p], attn_W[jr * 1024 + 1 + 2 * p]));
    }
    for (int i = gtid; i < 399360; i += NBLK * NTHR)
        ucstore(&wih0U[i], packh2(Wih0[2 * i], Wih0[2 * i + 1]));
    for (int i = gtid; i < 393216; i += NBLK * NTHR) {
        ucstore(&whh0U[i], packh2(Whh0[2 * i], Whh0[2 * i + 1]));
        ucstore(&wih1U[i], packh2(Wih1[2 * i], Wih1[2 * i + 1]));
        ucstore(&whh1U[i], packh2(Whh1[2 * i], Whh1[2 * i + 1]));
    }
    for (int i = gtid; i < 1048576; i += NBLK * NTHR)
        ucstore(&encU[i], packh2(enc[2 * i], enc[2 * i + 1]));
    if (gtid < 4096) {
        const int bb = gtid >> 8, p = gtid & 255;
        ucstore(&h0cU[gtid], packh2(hidden0[bb * 512 + 2 * p], hidden0[bb * 512 + 2 * p + 1]));
        ucstore(&h1cU[gtid], packh2(hidden0[8192 + bb * 512 + 2 * p], hidden0[8192 + bb * 512 + 2 * p + 1]));
    }
    if (gtid < 128) {
        const int bb = gtid >> 3, f = gtid & 7;
        cstore(&xinC[gtid], target[bb * 256 + f]);
    }
    lds[L_VW + tid] = v_w[tid];
    lds[L_VW + 256 + tid] = v_w[256 + tid];
    bar_sync(gridCnt, NBLK);

    // ===================== P2: enc_proj for own (b_att, 16 s) ================
    {
        for (int i = 0; i < 16; ++i) {
            const int idx = tid + i * 256;
            const int s = idx >> 8, p = idx & 255;
            ldsU[idx] = encU[(b_att * 256 + sgrp * 16 + s) * 256 + p];  // cached: fills L2
        }
        __syncthreads();
        float a0[16], a1[16];
        const float bb0 = attn_b[2 * tid], bb1 = attn_b[2 * tid + 1];
#pragma unroll
        for (int s = 0; s < 16; ++s) { a0[s] = bb0; a1[s] = bb1; }
        const unsigned* w0 = &aehU[(2 * tid) * 256];
        const unsigned* w1 = &aehU[(2 * tid + 1) * 256];
        for (int p = 0; p < 256; ++p) {
            const unsigned ww0 = w0[p], ww1 = w1[p];
#pragma unroll
            for (int s = 0; s < 16; ++s) {
                const unsigned e = ldsU[s * 256 + p];
                a0[s] = dot2(e, ww0, a0[s]);
                a1[s] = dot2(e, ww1, a1[s]);
            }
        }
        for (int s = 0; s < 16; ++s)  // plain store: only this block reads it
            encpU[(b_att * 256 + sgrp * 16 + s) * 256 + tid] = packh2(a0[s], a1[s]);
        __syncthreads();
    }

    // ===================== main recurrence ===================================
    for (int t = 0; t < kT; ++t) {
        const int par = t & 1;

        // ---- A: finalize out[t-1] (reducers) + stage h1 + hidp rows ----
        if (t > 0 && sgrp == 15 && tid < 64) {
            const int f = tid >> 3, sub = tid & 7;
            float acc = 0.f;
            for (int i = 0; i < 16; ++i)
                acc += cload(&outP[(b_att * 128 + sub * 16 + i) * 8 + f]);
            {
                const unsigned* wv = &weiCU[(par ^ 1) * 4096 + b_att * 256 + sub * 32];
                const float* ow = &outW[f * 1032 + 512 + sub * 64];
#pragma unroll 8
                for (int p = 0; p < 32; ++p) {
                    U32H u; u.u = ucload(&wv[p]);
                    acc += ow[2 * p] * (float)u.h.x + ow[2 * p + 1] * (float)u.h.y;
                }
            }
            if (sub == 7) {
#pragma unroll
                for (int ff = 0; ff < 8; ++ff)
                    acc += outW[f * 1032 + 1024 + ff] * cload(&xinC[(par ^ 1) * 128 + b_att * 8 + ff]);
                acc += outBias[f];
            }
            acc += __shfl_down(acc, 4, 8); acc += __shfl_down(acc, 2, 8); acc += __shfl_down(acc, 1, 8);
            if (sub == 0) {
                const float o = fmaxf(acc, 0.f);
                out[b_att * 256 + (t - 1) * 8 + f] = o;
                cstore(&xinC[par * 128 + b_att * 8 + f], o);
            }
        }
        for (int i = 0; i < 8; ++i) {
            const int idx = tid + i * 256;
            const int bb = idx >> 8, p = idx & 255;
            ldsU[L_H1 + bb * 264 + p] = ucload(&h1cU[par * 4096 + (half * 8 + bb) * 256 + p]);
        }
        __syncthreads();
        {
            const int unit = tid >> 3, sub = tid & 7;
            const int r = unit >> 3, bb = unit & 7;
            const uint4* wrow = (const uint4*)&whidU[(j * 4 + r) * 256 + sub * 32];
            const uint4* h1p = (const uint4*)&ldsU[L_H1 + bb * 264 + sub * 32];
            float acc = 0.f;
#pragma unroll
            for (int k4 = 0; k4 < 8; ++k4) {
                const uint4 hv = h1p[k4], wv = wrow[k4];
                acc = dot2(hv.x, wv.x, acc); acc = dot2(hv.y, wv.y, acc);
                acc = dot2(hv.z, wv.z, acc); acc = dot2(hv.w, wv.w, acc);
            }
            acc += __shfl_down(acc, 4, 8); acc += __shfl_down(acc, 2, 8); acc += __shfl_down(acc, 1, 8);
            if (sub == 0) cstore(&hidP[(half * 8 + bb) * 512 + j * 4 + r], acc);
        }
        bar_sync(halfCnt, 128 * (++bars));

        // ---- B: energy (16 s) + exp + weighted partials ----
        lds[L_HIDP + tid] = cload(&hidP[b_att * 512 + tid]);
        lds[L_HIDP + 256 + tid] = cload(&hidP[b_att * 512 + 256 + tid]);
        __syncthreads();
        {
            const int sloc = tid >> 4, sub = tid & 15;
            const unsigned* ep = &encpU[(b_att * 256 + sgrp * 16 + sloc) * 256];
            float acc = 0.f;
#pragma unroll 4
            for (int k2 = 0; k2 < 16; ++k2) {
                const int p = k2 * 16 + sub;
                U32H u; u.u = ep[p];
                acc += lds[L_VW + 2 * p] * ftanhf((float)u.h.x + lds[L_HIDP + 2 * p]);
                acc += lds[L_VW + 2 * p + 1] * ftanhf((float)u.h.y + lds[L_HIDP + 2 * p + 1]);
            }
            acc += __shfl_down(acc, 8, 16); acc += __shfl_down(acc, 4, 16);
            acc += __shfl_down(acc, 2, 16); acc += __shfl_down(acc, 1, 16);
            if (sub == 0) lds[L_ES + sloc] = __expf(acc);  // |score|<=~20: fp32-safe
        }
        __syncthreads();
        {
            float wp0 = 0.f, wp1 = 0.f;
            const unsigned* er = &encU[(b_att * 256 + sgrp * 16) * 256 + tid];
#pragma unroll
            for (int sl = 0; sl < 16; ++sl) {
                U32H u; u.u = er[sl * 256];
                const float es = lds[L_ES + sl];
                wp0 += es * (float)u.h.x; wp1 += es * (float)u.h.y;
            }
            cstore(&wpart[(b_att * 16 + sgrp) * 512 + 2 * tid], wp0);
            cstore(&wpart[(b_att * 16 + sgrp) * 512 + 2 * tid + 1], wp1);
            if (tid == 0) {
                float l = 0.f;
#pragma unroll
                for (int i = 0; i < 16; ++i) l += lds[L_ES + i];
                cstore(&lpart[b_att * 16 + sgrp], l);
            }
        }
        bar_sync(halfCnt, 128 * (++bars));

        // ---- C: cooperative weighted reduce (16 blocks x 16 col-pairs) ----
        if (tid < 16) lds[L_LP + tid] = cload(&lpart[b_att * 16 + tid]);
        __syncthreads();
        {
            float L = 0.f;
#pragma unroll
            for (int i = 0; i < 16; ++i) L += lds[L_LP + i];
            const float inv = 1.f / L;
            const int pi = tid >> 4, sg2 = tid & 15;
            const int cp = sgrp * 16 + pi;
            float s0 = cload(&wpart[(b_att * 16 + sg2) * 512 + 2 * cp]);
            float s1 = cload(&wpart[(b_att * 16 + sg2) * 512 + 2 * cp + 1]);
            s0 += __shfl_down(s0, 8, 16); s0 += __shfl_down(s0, 4, 16);
            s0 += __shfl_down(s0, 2, 16); s0 += __shfl_down(s0, 1, 16);
            s1 += __shfl_down(s1, 8, 16); s1 += __shfl_down(s1, 4, 16);
            s1 += __shfl_down(s1, 2, 16); s1 += __shfl_down(s1, 1, 16);
            if (sg2 == 0) ucstore(&weiCU[par * 4096 + b_att * 256 + cp], packh2(s0 * inv, s1 * inv));
        }
        bar_sync(halfCnt, 128 * (++bars));

        // ---- D: GRU0 rows [4j,4j+4) for 8 b ----
        if (tid < 32) {
            const int bb = tid >> 2, q4 = tid & 3;
            const float f0 = cload(&xinC[par * 128 + (half * 8 + bb) * 8 + 2 * q4]);
            const float f1 = cload(&xinC[par * 128 + (half * 8 + bb) * 8 + 2 * q4 + 1]);
            ldsU[L_HX + bb * 264 + q4] = packh2(f0, f1);
            ldsU[L_HX + bb * 264 + 260 + q4] = 0u;  // zero pad (x length 260 -> 264)
        }
        for (int i = 0; i < 8; ++i) {
            const int idx = tid + i * 256;
            const int bb = idx >> 8, p = idx & 255;
            ldsU[L_HX + bb * 264 + 4 + p] = ucload(&weiCU[par * 4096 + (half * 8 + bb) * 256 + p]);
            ldsU[L_H0 + bb * 264 + p] = ucload(&h0cU[par * 4096 + (half * 8 + bb) * 256 + p]);
        }
        __syncthreads();
        if (tid < 192) {
            const int u = tid >> 1, sub = tid & 1;
            const int bb = u & 7, gh = u >> 3;
            const int gate = gh >> 2, hr = gh & 3;
            const int grow = gate * 512 + j * 4 + hr;
            const uint4* wx = (const uint4*)&wih0U[grow * 260 + sub * 132];
            const uint4* xp = (const uint4*)&ldsU[L_HX + bb * 264 + sub * 132];
            float ax = 0.f;
#pragma unroll 11
            for (int k4 = 0; k4 < 33; ++k4) {  // tail pairs are zero-padded in x
                const uint4 xv = xp[k4], wv = wx[k4];
                ax = dot2(xv.x, wv.x, ax); ax = dot2(xv.y, wv.y, ax);
                ax = dot2(xv.z, wv.z, ax); ax = dot2(xv.w, wv.w, ax);
            }
            const uint4* wh = (const uint4*)&whh0U[grow * 256 + sub * 128];
            const uint4* hp = (const uint4*)&ldsU[L_H0 + bb * 264 + sub * 128];
            float ah = 0.f;
#pragma unroll 8
            for (int k4 = 0; k4 < 32; ++k4) {
                const uint4 hv = hp[k4], wv = wh[k4];
                ah = dot2(hv.x, wv.x, ah); ah = dot2(hv.y, wv.y, ah);
                ah = dot2(hv.z, wv.z, ah); ah = dot2(hv.w, wv.w, ah);
            }
            ax += __shfl_down(ax, 1, 2); ah += __shfl_down(ah, 1, 2);
            if (sub == 0) {
                lds[L_AX + gh * 8 + bb] = ax + bih0[grow];
                lds[L_AH + gh * 8 + bb] = ah + bhh0[grow];
            }
        }
        __syncthreads();
        if (tid < 32) {
            const int hr = tid >> 3, bb = tid & 7;
            const float r = fsig(lds[L_AX + hr * 8 + bb] + lds[L_AH + hr * 8 + bb]);
            const float z = fsig(lds[L_AX + (4 + hr) * 8 + bb] + lds[L_AH + (4 + hr) * 8 + bb]);
            const float n = ftanhf(lds[L_AX + (8 + hr) * 8 + bb] + r * lds[L_AH + (8 + hr) * 8 + bb]);
            U32H u; u.u = ldsU[L_H0 + bb * 264 + j * 2 + (hr >> 1)];
            const float hold = (hr & 1) ? (float)u.h.y : (float)u.h.x;
            lds[L_HS + hr * 8 + bb] = (1.f - z) * n + z * hold;
        }
        __syncthreads();
        if (tid < 16) {
            const int pp = tid >> 3, bb = tid & 7;
            ucstore(&h0cU[(par ^ 1) * 4096 + (half * 8 + bb) * 256 + j * 2 + pp],
                    packh2(lds[L_HS + (2 * pp) * 8 + bb], lds[L_HS + (2 * pp + 1) * 8 + bb]));
        }
        bar_sync(halfCnt, 128 * (++bars));

        // ---- E: GRU1 rows + h1-slice out partials ----
        for (int i = 0; i < 8; ++i) {
            const int idx = tid + i * 256;
            const int bb = idx >> 8, p = idx & 255;
            ldsU[L_HX + bb * 264 + p] = ucload(&h0cU[(par ^ 1) * 4096 + (half * 8 + bb) * 256 + p]);
        }
        __syncthreads();
        if (tid < 192) {
            const int u = tid >> 1, sub = tid & 1;
            const int bb = u & 7, gh = u >> 3;
            const int gate = gh >> 2, hr = gh & 3;
            const int grow = gate * 512 + j * 4 + hr;
            const uint4* wx = (const uint4*)&wih1U[grow * 256 + sub * 128];
            const uint4* xp = (const uint4*)&ldsU[L_HX + bb * 264 + sub * 128];
            float ax = 0.f;
#pragma unroll 8
            for (int k4 = 0; k4 < 32; ++k4) {
                const uint4 xv = xp[k4], wv = wx[k4];
                ax = dot2(xv.x, wv.x, ax); ax = dot2(xv.y, wv.y, ax);
                ax = dot2(xv.z, wv.z, ax); ax = dot2(xv.w, wv.w, ax);
            }
            const uint4* wh = (const uint4*)&whh1U[grow * 256 + sub * 128];
            const uint4* hp = (const uint4*)&ldsU[L_H1 + bb * 264 + sub * 128];
            float ah = 0.f;
#pragma unroll 8
            for (int k4 = 0; k4 < 32; ++k4) {
                const uint4 hv = hp[k4], wv = wh[k4];
                ah = dot2(hv.x, wv.x, ah); ah = dot2(hv.y, wv.y, ah);
                ah = dot2(hv.z, wv.z, ah); ah = dot2(hv.w, wv.w, ah);
            }
            ax += __shfl_down(ax, 1, 2); ah += __shfl_down(ah, 1, 2);
            if (sub == 0) {
                lds[L_AX + gh * 8 + bb] = ax + bih1[grow];
                lds[L_AH + gh * 8 + bb] = ah + bhh1[grow];
            }
        }
        __syncthreads();
        if (tid < 32) {
            const int hr = tid >> 3, bb = tid & 7;
            const float r = fsig(lds[L_AX + hr * 8 + bb] + lds[L_AH + hr * 8 + bb]);
            const float z = fsig(lds[L_AX + (4 + hr) * 8 + bb] + lds[L_AH + (4 + hr) * 8 + bb]);
            const float n = ftanhf(lds[L_AX + (8 + hr) * 8 + bb] + r * lds[L_AH + (8 + hr) * 8 + bb]);
            U32H u; u.u = ldsU[L_H1 + bb * 264 + j * 2 + (hr >> 1)];
            const float hold = (hr & 1) ? (float)u.h.y : (float)u.h.x;
            lds[L_HS + hr * 8 + bb] = (1.f - z) * n + z * hold;
        }
        __syncthreads();
        if (tid < 16) {
            const int pp = tid >> 3, bb = tid & 7;
            ucstore(&h1cU[(par ^ 1) * 4096 + (half * 8 + bb) * 256 + j * 2 + pp],
                    packh2(lds[L_HS + (2 * pp) * 8 + bb], lds[L_HS + (2 * pp + 1) * 8 + bb]));
        }
        if (tid < 64) {
            const int f = tid >> 3, bb = tid & 7;
            float acc = 0.f;
#pragma unroll
            for (int hr = 0; hr < 4; ++hr)
                acc += outW[f * 1032 + j * 4 + hr] * lds[L_HS + hr * 8 + bb];
            cstore(&outP[((half * 8 + bb) * 128 + j) * 8 + f], acc);
        }
        bar_sync(halfCnt, 128 * (++bars));
    }

    // ---- epilogue: finalize out[31] (par(t=32) = 0) ----
    if (sgrp == 15 && tid < 64) {
        const int f = tid >> 3, sub = tid & 7;
        float acc = 0.f;
        for (int i = 0; i < 16; ++i)
            acc += cload(&outP[(b_att * 128 + sub * 16 + i) * 8 + f]);
        {
            const unsigned* wv = &weiCU[1 * 4096 + b_att * 256 + sub * 32];
            const float* ow = &outW[f * 1032 + 512 + sub * 64];
#pragma unroll 8
            for (int p = 0; p < 32; ++p) {
                U32H u; u.u = ucload(&wv[p]);
                acc += ow[2 * p] * (float)u.h.x + ow[2 * p + 1] * (float)u.h.y;
            }
        }
        if (sub == 7) {
#pragma unroll
            for (int ff = 0; ff < 8; ++ff)
                acc += outW[f * 1032 + 1024 + ff] * cload(&xinC[1 * 128 + b_att * 8 + ff]);
            acc += outBias[f];
        }
        acc += __shfl_down(acc, 4, 8); acc += __shfl_down(acc, 2, 8); acc += __shfl_down(acc, 1, 8);
        if (sub == 0) out[b_att * 256 + 31 * 8 + f] = fmaxf(acc, 0.f);
    }
}

extern "C" void kernel_launch(void* const* d_in, const int* in_sizes, int n_in,
                              void* d_out, int out_size, void* d_ws, size_t ws_size,
                              hipStream_t stream) {
    (void)in_sizes; (void)n_in; (void)out_size; (void)ws_size;
    hipMemsetAsync(d_ws, 0, 4096, stream);  // zero barrier counters
    decoder_kernel<<<NBLK, NTHR, 0, stream>>>(
        (const float*)d_in[0], (const float*)d_in[1], (const float*)d_in[2],
        (const float*)d_in[3], (const float*)d_in[4], (const float*)d_in[5],
        (const float*)d_in[6], (const float*)d_in[7], (const float*)d_in[8],
        (const float*)d_in[9], (const float*)d_in[10], (const float*)d_in[11],
        (const float*)d_in[12], (const float*)d_in[13], (const float*)d_in[14],
        (const float*)d_in[15], (float*)d_out, (float*)d_ws);
}

// Round 6
// 1193.026 us; speedup vs baseline: 3.5360x; 1.2996x over previous
//
#include <hip/hip_runtime.h>

// DecoderWithAttention: B=16, T=32, F=8, S_ENC=256, H=512, L=2.
// R6 = R5 skeleton (2 halves x 128 row-slice blocks, 256 thr) minus stage C:
//  - Stage B atomicAdds unnormalized weighted partials + L into per-parity fp32
//    accumulators at the coherence point; stage D normalizes on load.
//    (kills 1 of 5 barriers/step and the 512KB/step wpart HBM round trip)
//  - GRU layer-0 weights + whid + biases + own outW cols pinned in LDS (~30KB;
//    total static LDS 59.8KB). Layer-1 weights stay L2-resident (cached loads).
//  - Prologue uses plain cached stores + ONE agent release fence per block at
//    the grid barrier (single wbl2/inv per block, once per launch).
//  - out base term (wei+xin+bias) computed in stage D by sgrp==14 block;
//    finalize (sum 128 outP partials + relu) in stage A of t+1 by sgrp==15.

namespace {
constexpr int kB = 16, kT = 32, kF = 8, kS = 256, kH = 512;
constexpr int NBLK = 256, NTHR = 256;

// ws float offsets. [0..63]: barrier counters (half0@0, half1@32, grid@64).
constexpr int OFF_AEH   = 1024;                   // [512][256] u32 attn_W[:,512:]
constexpr int OFF_WHID  = OFF_AEH + 131072;       // [512][256] u32 attn_W[:,:512]
constexpr int OFF_WIH0  = OFF_WHID + 131072;      // [1536][260] u32
constexpr int OFF_WHH0  = OFF_WIH0 + 399360;      // [1536][256] u32
constexpr int OFF_WIH1  = OFF_WHH0 + 393216;      // [1536][256] u32
constexpr int OFF_WHH1  = OFF_WIH1 + 393216;      // [1536][256] u32
constexpr int OFF_ENCH  = OFF_WHH1 + 393216;      // [4096][256] u32 enc f16
constexpr int OFF_ENCP  = OFF_ENCH + 1048576;     // [4096][256] u32 enc_proj f16
constexpr int OFF_HIDP  = OFF_ENCP + 1048576;     // [16][512] f32
constexpr int OFF_WEIA  = OFF_HIDP + 8192;        // [2][16][512] f32 accumulators
constexpr int OFF_LACC  = OFF_WEIA + 16384;       // [2][16] f32 accumulators
constexpr int OFF_OUTB  = OFF_LACC + 32;          // [2][16][8] f32
constexpr int OFF_H0C   = OFF_OUTB + 256;         // [2][16][256] u32
constexpr int OFF_H1C   = OFF_H0C + 8192;         // [2][16][256] u32
constexpr int OFF_XINC  = OFF_H1C + 8192;         // [2][16][8] f32
constexpr int OFF_OUTP  = OFF_XINC + 256;         // [16][128][8] f32

// LDS float/u32 offsets (shared indexing; total 14960 floats = 59.8 KB)
constexpr int L_WIH0 = 0;        // [12][264] u32 (260 + 4 zero pad)
constexpr int L_WHH0 = 3168;     // [12][256] u32
constexpr int L_WHID = 6240;     // [4][256] u32
constexpr int L_BIH0 = 7264, L_BHH0 = 7276, L_BIH1 = 7288, L_BHH1 = 7300;
constexpr int L_OOW  = 7312;     // [8][4] f32 outW own cols
constexpr int L_VW   = 7344;     // [512] f32
constexpr int L_H1   = 7856;     // [8][264] u32 (persists A->E)
constexpr int L_HX   = 9968;     // [8][264] u32
constexpr int L_H0   = 12080;    // [8][264] u32
constexpr int L_HIDP = 14192;    // [512] f32
constexpr int L_ES   = 14704;    // [16]
constexpr int L_AX   = 14720;    // [96]
constexpr int L_AH   = 14816;    // [96]
constexpr int L_HS   = 14912;    // [32]
constexpr int L_XINL = 14944;    // [8]
constexpr int L_INV  = 14952;    // [8]
constexpr int LDS_FLOATS = 14960;
}  // namespace

typedef _Float16 h2 __attribute__((ext_vector_type(2)));
union U32H { unsigned u; h2 h; };

__device__ __forceinline__ float dot2(unsigned a, unsigned b, float acc) {
    U32H ua, ub; ua.u = a; ub.u = b;
#if __has_builtin(__builtin_amdgcn_fdot2)
    return __builtin_amdgcn_fdot2(ua.h, ub.h, acc, false);
#else
    return acc + (float)ua.h.x * (float)ub.h.x + (float)ua.h.y * (float)ub.h.y;
#endif
}
__device__ __forceinline__ unsigned packh2(float a, float b) {
    U32H u; u.h = h2{(_Float16)a, (_Float16)b}; return u.u;
}
__device__ __forceinline__ float fsig(float x) { return 1.0f / (1.0f + __expf(-x)); }
__device__ __forceinline__ float ftanhf(float x) {
    float e = __expf(2.0f * x);
    return 1.0f - 2.0f / (e + 1.0f);
}
// Uncached per-access comm ops (sc0 sc1 -> coherence point).
__device__ __forceinline__ float cload(const float* p) {
    return __hip_atomic_load(p, __ATOMIC_RELAXED, __HIP_MEMORY_SCOPE_SYSTEM);
}
__device__ __forceinline__ void cstore(float* p, float v) {
    __hip_atomic_store(p, v, __ATOMIC_RELAXED, __HIP_MEMORY_SCOPE_SYSTEM);
}
__device__ __forceinline__ unsigned ucload(const unsigned* p) {
    return __hip_atomic_load(p, __ATOMIC_RELAXED, __HIP_MEMORY_SCOPE_SYSTEM);
}

// Main-loop barrier (validated R2/R4/R5): no cache maintenance.
__device__ __forceinline__ void bar_sync(unsigned* cnt, unsigned target) {
    __syncthreads();
    if (threadIdx.x == 0) {
        __builtin_amdgcn_fence(__ATOMIC_RELEASE, "workgroup");
        __builtin_amdgcn_s_waitcnt(0);
        __hip_atomic_fetch_add(cnt, 1u, __ATOMIC_RELAXED, __HIP_MEMORY_SCOPE_SYSTEM);
        while (__hip_atomic_load(cnt, __ATOMIC_RELAXED, __HIP_MEMORY_SCOPE_SYSTEM) < target)
            __builtin_amdgcn_s_sleep(1);
        __builtin_amdgcn_fence(__ATOMIC_ACQUIRE, "workgroup");
    }
    __syncthreads();
}

// Prologue barrier: one agent-scope wbl2 (release) / inv (acquire) per block.
__device__ __forceinline__ void bar_sync_flush(unsigned* cnt, unsigned target) {
    __syncthreads();
    if (threadIdx.x == 0) {
        __builtin_amdgcn_fence(__ATOMIC_RELEASE, "agent");
        __hip_atomic_fetch_add(cnt, 1u, __ATOMIC_RELAXED, __HIP_MEMORY_SCOPE_SYSTEM);
        while (__hip_atomic_load(cnt, __ATOMIC_RELAXED, __HIP_MEMORY_SCOPE_SYSTEM) < target)
            __builtin_amdgcn_s_sleep(8);
        __builtin_amdgcn_fence(__ATOMIC_ACQUIRE, "agent");
    }
    __syncthreads();
}

__global__ __launch_bounds__(NTHR) void decoder_kernel(
    const float* __restrict__ target, const float* __restrict__ hidden0,
    const float* __restrict__ enc, const float* __restrict__ attn_W,
    const float* __restrict__ attn_b, const float* __restrict__ v_w,
    const float* __restrict__ Wih0, const float* __restrict__ Whh0,
    const float* __restrict__ bih0, const float* __restrict__ bhh0,
    const float* __restrict__ Wih1, const float* __restrict__ Whh1,
    const float* __restrict__ bih1, const float* __restrict__ bhh1,
    const float* __restrict__ outW, const float* __restrict__ outBias,
    float* __restrict__ out, float* __restrict__ ws) {
    const int tid = threadIdx.x, bid = blockIdx.x;
    const int half = bid >> 7, j = bid & 127;
    const int bloc = j >> 4, sgrp = j & 15;
    const int b_att = half * 8 + bloc;
    unsigned* halfCnt = (unsigned*)ws + 32 * half;
    unsigned* gridCnt = (unsigned*)ws + 64;
    unsigned bars = 0;

    unsigned* aehU  = (unsigned*)(ws + OFF_AEH);
    unsigned* whidU = (unsigned*)(ws + OFF_WHID);
    unsigned* wih0U = (unsigned*)(ws + OFF_WIH0);
    unsigned* whh0U = (unsigned*)(ws + OFF_WHH0);
    unsigned* wih1U = (unsigned*)(ws + OFF_WIH1);
    unsigned* whh1U = (unsigned*)(ws + OFF_WHH1);
    unsigned* encU  = (unsigned*)(ws + OFF_ENCH);
    unsigned* encpU = (unsigned*)(ws + OFF_ENCP);
    float* hidP  = ws + OFF_HIDP;
    float* weiA  = ws + OFF_WEIA;
    float* lacc  = ws + OFF_LACC;
    float* outBs = ws + OFF_OUTB;
    unsigned* h0cU = (unsigned*)(ws + OFF_H0C);
    unsigned* h1cU = (unsigned*)(ws + OFF_H1C);
    float* xinC = ws + OFF_XINC;
    float* outP = ws + OFF_OUTP;

    __shared__ __align__(16) float lds[LDS_FLOATS];
    unsigned* ldsU = (unsigned*)lds;
    const int gtid = bid * NTHR + tid;

    // ===================== P1: f16 pack + state + accumulator init (plain) ====
    for (int i = gtid; i < 131072; i += NBLK * NTHR) {
        const int jr = i >> 8, p = i & 255;
        aehU[i]  = packh2(attn_W[jr * 1024 + 512 + 2 * p], attn_W[jr * 1024 + 513 + 2 * p]);
        whidU[i] = packh2(attn_W[jr * 1024 + 2 * p], attn_W[jr * 1024 + 1 + 2 * p]);
    }
    for (int i = gtid; i < 399360; i += NBLK * NTHR)
        wih0U[i] = packh2(Wih0[2 * i], Wih0[2 * i + 1]);
    for (int i = gtid; i < 393216; i += NBLK * NTHR) {
        whh0U[i] = packh2(Whh0[2 * i], Whh0[2 * i + 1]);
        wih1U[i] = packh2(Wih1[2 * i], Wih1[2 * i + 1]);
        whh1U[i] = packh2(Whh1[2 * i], Whh1[2 * i + 1]);
    }
    for (int i = gtid; i < 1048576; i += NBLK * NTHR)
        encU[i] = packh2(enc[2 * i], enc[2 * i + 1]);
    if (gtid < 4096) {
        const int bb = gtid >> 8, p = gtid & 255;
        h0cU[gtid] = packh2(hidden0[bb * 512 + 2 * p], hidden0[bb * 512 + 2 * p + 1]);
        h1cU[gtid] = packh2(hidden0[8192 + bb * 512 + 2 * p], hidden0[8192 + bb * 512 + 2 * p + 1]);
    }
    if (gtid < 128) {
        const int bb = gtid >> 3, f = gtid & 7;
        xinC[gtid] = target[bb * 256 + f];
    }
    for (int i = gtid; i < 16672; i += NBLK * NTHR)  // weiA + lacc + outBs zero
        ws[OFF_WEIA + i] = 0.f;
    bar_sync_flush(gridCnt, NBLK);  // one wbl2/inv per block

    // ===================== P2: enc_proj for own (b_att, 16 s) =================
    {
        for (int i = 0; i < 16; ++i) {
            const int idx = tid + i * 256;
            const int s = idx >> 8, p = idx & 255;
            ldsU[idx] = encU[(b_att * 256 + sgrp * 16 + s) * 256 + p];
        }
        __syncthreads();
        float a0[16], a1[16];
        const float bb0 = attn_b[2 * tid], bb1 = attn_b[2 * tid + 1];
#pragma unroll
        for (int s = 0; s < 16; ++s) { a0[s] = bb0; a1[s] = bb1; }
        const unsigned* w0 = &aehU[(2 * tid) * 256];
        const unsigned* w1 = &aehU[(2 * tid + 1) * 256];
        for (int p = 0; p < 256; ++p) {
            const unsigned ww0 = w0[p], ww1 = w1[p];
#pragma unroll
            for (int s = 0; s < 16; ++s) {
                const unsigned e = ldsU[s * 256 + p];
                a0[s] = dot2(e, ww0, a0[s]);
                a1[s] = dot2(e, ww1, a1[s]);
            }
        }
        for (int s = 0; s < 16; ++s)  // self-read only
            encpU[(b_att * 256 + sgrp * 16 + s) * 256 + tid] = packh2(a0[s], a1[s]);
        __syncthreads();
    }

    // ===================== P3: pin layer-0 weights + whid + misc in LDS =======
    for (int gh = 0; gh < 12; ++gh) {
        const int grow = (gh >> 2) * 512 + j * 4 + (gh & 3);
        for (int p = tid; p < 260; p += 256) ldsU[L_WIH0 + gh * 264 + p] = wih0U[grow * 260 + p];
        if (tid < 4) ldsU[L_WIH0 + gh * 264 + 260 + tid] = 0u;
        ldsU[L_WHH0 + gh * 256 + tid] = whh0U[grow * 256 + tid];
    }
    for (int r = 0; r < 4; ++r) ldsU[L_WHID + r * 256 + tid] = whidU[(j * 4 + r) * 256 + tid];
    if (tid < 12) {
        const int grow = (tid >> 2) * 512 + j * 4 + (tid & 3);
        lds[L_BIH0 + tid] = bih0[grow]; lds[L_BHH0 + tid] = bhh0[grow];
        lds[L_BIH1 + tid] = bih1[grow]; lds[L_BHH1 + tid] = bhh1[grow];
    }
    if (tid < 32) lds[L_OOW + tid] = outW[(tid >> 2) * 1032 + j * 4 + (tid & 3)];
    lds[L_VW + tid] = v_w[tid];
    lds[L_VW + 256 + tid] = v_w[256 + tid];
    __syncthreads();

    // ===================== main recurrence: A | B | D | E =====================
    for (int t = 0; t < kT; ++t) {
        const int par = t & 1;

        // ---- A: finalize out[t-1] + stage h1 + hidp rows ----
        if (t > 0 && sgrp == 15 && tid < 64) {
            const int f = tid >> 3, sub = tid & 7;
            float acc = 0.f;
            for (int i = 0; i < 16; ++i)
                acc += cload(&outP[(b_att * 128 + sub * 16 + i) * 8 + f]);
            acc += __shfl_down(acc, 4, 8); acc += __shfl_down(acc, 2, 8); acc += __shfl_down(acc, 1, 8);
            if (sub == 0) {
                acc += cload(&outBs[(par ^ 1) * 128 + b_att * 8 + f]);
                const float o = fmaxf(acc, 0.f);
                out[b_att * 256 + (t - 1) * 8 + f] = o;
                cstore(&xinC[par * 128 + b_att * 8 + f], o);
            }
        }
        for (int i = 0; i < 8; ++i) {
            const int idx = tid + i * 256;
            const int bb = idx >> 8, p = idx & 255;
            ldsU[L_H1 + bb * 264 + p] = ucload(&h1cU[par * 4096 + (half * 8 + bb) * 256 + p]);
        }
        __syncthreads();
        {
            const int unit = tid >> 3, sub = tid & 7;
            const int r = unit >> 3, bb = unit & 7;
            const uint4* wrow = (const uint4*)&ldsU[L_WHID + r * 256 + sub * 32];
            const uint4* h1p = (const uint4*)&ldsU[L_H1 + bb * 264 + sub * 32];
            float acc = 0.f;
#pragma unroll
            for (int k4 = 0; k4 < 8; ++k4) {
                const uint4 hv = h1p[k4], wv = wrow[k4];
                acc = dot2(hv.x, wv.x, acc); acc = dot2(hv.y, wv.y, acc);
                acc = dot2(hv.z, wv.z, acc); acc = dot2(hv.w, wv.w, acc);
            }
            acc += __shfl_down(acc, 4, 8); acc += __shfl_down(acc, 2, 8); acc += __shfl_down(acc, 1, 8);
            if (sub == 0) cstore(&hidP[(half * 8 + bb) * 512 + j * 4 + r], acc);
        }
        bar_sync(halfCnt, 128 * (++bars));

        // ---- B: energy (16 s) + exp + atomicAdd weighted/L ----
        lds[L_HIDP + tid] = cload(&hidP[b_att * 512 + tid]);
        lds[L_HIDP + 256 + tid] = cload(&hidP[b_att * 512 + 256 + tid]);
        __syncthreads();
        {
            const int sloc = tid >> 4, sub = tid & 15;
            const unsigned* ep = &encpU[(b_att * 256 + sgrp * 16 + sloc) * 256];
            float acc = 0.f;
#pragma unroll 4
            for (int k2 = 0; k2 < 16; ++k2) {
                const int p = k2 * 16 + sub;
                U32H u; u.u = ep[p];
                acc += lds[L_VW + 2 * p] * ftanhf((float)u.h.x + lds[L_HIDP + 2 * p]);
                acc += lds[L_VW + 2 * p + 1] * ftanhf((float)u.h.y + lds[L_HIDP + 2 * p + 1]);
            }
            acc += __shfl_down(acc, 8, 16); acc += __shfl_down(acc, 4, 16);
            acc += __shfl_down(acc, 2, 16); acc += __shfl_down(acc, 1, 16);
            if (sub == 0) lds[L_ES + sloc] = __expf(acc);  // |score|<=~20: fp32-safe
        }
        __syncthreads();
        {
            float wp0 = 0.f, wp1 = 0.f;
            const unsigned* er = &encU[(b_att * 256 + sgrp * 16) * 256 + tid];
#pragma unroll
            for (int sl = 0; sl < 16; ++sl) {
                U32H u; u.u = er[sl * 256];
                const float es = lds[L_ES + sl];
                wp0 += es * (float)u.h.x; wp1 += es * (float)u.h.y;
            }
            atomicAdd(&weiA[par * 8192 + b_att * 512 + 2 * tid], wp0);
            atomicAdd(&weiA[par * 8192 + b_att * 512 + 2 * tid + 1], wp1);
            if (tid == 0) {
                float l = 0.f;
#pragma unroll
                for (int i = 0; i < 16; ++i) l += lds[L_ES + i];
                atomicAdd(&lacc[par * 16 + b_att], l);
            }
        }
        bar_sync(halfCnt, 128 * (++bars));

        // ---- D: normalize wei + GRU0 rows + out base term ----
        if (tid < 8) {
            const float L = cload(&lacc[par * 16 + half * 8 + tid]);
            lds[L_INV + tid] = 1.f / L;
        }
        if (sgrp == 14 && tid >= 8 && tid < 16)
            lds[L_XINL + tid - 8] = cload(&xinC[par * 128 + b_att * 8 + (tid - 8)]);
        if (tid >= 32 && tid < 64) {
            const int bb = (tid - 32) >> 2, q4 = (tid - 32) & 3;
            const float f0 = cload(&xinC[par * 128 + (half * 8 + bb) * 8 + 2 * q4]);
            const float f1 = cload(&xinC[par * 128 + (half * 8 + bb) * 8 + 2 * q4 + 1]);
            ldsU[L_HX + bb * 264 + q4] = packh2(f0, f1);
            ldsU[L_HX + bb * 264 + 260 + q4] = 0u;  // zero tail pad
        }
        for (int i = 0; i < 8; ++i) {
            const int idx = tid + i * 256;
            const int bb = idx >> 8, p = idx & 255;
            ldsU[L_H0 + bb * 264 + p] = ucload(&h0cU[par * 4096 + (half * 8 + bb) * 256 + p]);
        }
        __syncthreads();
        for (int i = 0; i < 8; ++i) {
            const int idx = tid + i * 256;
            const int bb = idx >> 8, p = idx & 255;
            const float w0 = cload(&weiA[par * 8192 + (half * 8 + bb) * 512 + 2 * p]);
            const float w1 = cload(&weiA[par * 8192 + (half * 8 + bb) * 512 + 2 * p + 1]);
            const float inv = lds[L_INV + bb];
            ldsU[L_HX + bb * 264 + 4 + p] = packh2(w0 * inv, w1 * inv);
        }
        __syncthreads();
        if (tid < 192) {
            const int u = tid >> 1, sub = tid & 1;
            const int bb = u & 7, gh = u >> 3;
            const uint4* wx = (const uint4*)&ldsU[L_WIH0 + gh * 264 + sub * 132];
            const uint4* xp = (const uint4*)&ldsU[L_HX + bb * 264 + sub * 132];
            float ax = 0.f;
#pragma unroll 11
            for (int k4 = 0; k4 < 33; ++k4) {
                const uint4 xv = xp[k4], wv = wx[k4];
                ax = dot2(xv.x, wv.x, ax); ax = dot2(xv.y, wv.y, ax);
                ax = dot2(xv.z, wv.z, ax); ax = dot2(xv.w, wv.w, ax);
            }
            const uint4* wh = (const uint4*)&ldsU[L_WHH0 + gh * 256 + sub * 128];
            const uint4* hp = (const uint4*)&ldsU[L_H0 + bb * 264 + sub * 128];
            float ah = 0.f;
#pragma unroll 8
            for (int k4 = 0; k4 < 32; ++k4) {
                const uint4 hv = hp[k4], wv = wh[k4];
                ah = dot2(hv.x, wv.x, ah); ah = dot2(hv.y, wv.y, ah);
                ah = dot2(hv.z, wv.z, ah); ah = dot2(hv.w, wv.w, ah);
            }
            ax += __shfl_down(ax, 1, 2); ah += __shfl_down(ah, 1, 2);
            if (sub == 0) {
                lds[L_AX + gh * 8 + bb] = ax + lds[L_BIH0 + gh];
                lds[L_AH + gh * 8 + bb] = ah + lds[L_BHH0 + gh];
            }
        }
        __syncthreads();
        if (tid < 32) {
            const int hr = tid >> 3, bb = tid & 7;
            const float r = fsig(lds[L_AX + hr * 8 + bb] + lds[L_AH + hr * 8 + bb]);
            const float z = fsig(lds[L_AX + (4 + hr) * 8 + bb] + lds[L_AH + (4 + hr) * 8 + bb]);
            const float n = ftanhf(lds[L_AX + (8 + hr) * 8 + bb] + r * lds[L_AH + (8 + hr) * 8 + bb]);
            U32H u; u.u = ldsU[L_H0 + bb * 264 + j * 2 + (hr >> 1)];
            const float hold = (hr & 1) ? (float)u.h.y : (float)u.h.x;
            lds[L_HS + hr * 8 + bb] = (1.f - z) * n + z * hold;
        }
        if (sgrp == 14 && tid >= 64 && tid < 128) {
            const int f = (tid - 64) >> 3, sub2 = tid & 7;
            float acc = 0.f;
            const float* ow = &outW[f * 1032 + 512 + sub2 * 64];
#pragma unroll 8
            for (int p2 = 0; p2 < 32; ++p2) {
                U32H u; u.u = ldsU[L_HX + bloc * 264 + 4 + sub2 * 32 + p2];
                acc += ow[2 * p2] * (float)u.h.x + ow[2 * p2 + 1] * (float)u.h.y;
            }
            acc += __shfl_down(acc, 4, 8); acc += __shfl_down(acc, 2, 8); acc += __shfl_down(acc, 1, 8);
            if (sub2 == 0) {
#pragma unroll
                for (int ff = 0; ff < 8; ++ff)
                    acc += outW[f * 1032 + 1024 + ff] * lds[L_XINL + ff];
                cstore(&outBs[par * 128 + b_att * 8 + f], acc + outBias[f]);
            }
        }
        __syncthreads();
        if (tid < 16) {
            const int pp = tid >> 3, bb = tid & 7;
            ((unsigned*)(ws + OFF_H0C))[0] = ((unsigned*)(ws + OFF_H0C))[0];  // no-op guard
        }
        if (tid < 16) {
            const int pp = tid >> 3, bb = tid & 7;
            __hip_atomic_store(&h0cU[(par ^ 1) * 4096 + (half * 8 + bb) * 256 + j * 2 + pp],
                               packh2(lds[L_HS + (2 * pp) * 8 + bb], lds[L_HS + (2 * pp + 1) * 8 + bb]),
                               __ATOMIC_RELAXED, __HIP_MEMORY_SCOPE_SYSTEM);
        }
        bar_sync(halfCnt, 128 * (++bars));

        // ---- E: GRU1 rows + outP partials + accumulator re-zero ----
        for (int i = 0; i < 8; ++i) {
            const int idx = tid + i * 256;
            const int bb = idx >> 8, p = idx & 255;
            ldsU[L_HX + bb * 264 + p] = ucload(&h0cU[(par ^ 1) * 4096 + (half * 8 + bb) * 256 + p]);
        }
        __syncthreads();
        if (tid < 192) {
            const int u = tid >> 1, sub = tid & 1;
            const int bb = u & 7, gh = u >> 3;
            const int grow = (gh >> 2) * 512 + j * 4 + (gh & 3);
            const uint4* wx = (const uint4*)&wih1U[grow * 256 + sub * 128];
            const uint4* xp = (const uint4*)&ldsU[L_HX + bb * 264 + sub * 128];
            float ax = 0.f;
#pragma unroll 8
            for (int k4 = 0; k4 < 32; ++k4) {
                const uint4 xv = xp[k4], wv = wx[k4];
                ax = dot2(xv.x, wv.x, ax); ax = dot2(xv.y, wv.y, ax);
                ax = dot2(xv.z, wv.z, ax); ax = dot2(xv.w, wv.w, ax);
            }
            const uint4* wh = (const uint4*)&whh1U[grow * 256 + sub * 128];
            const uint4* hp = (const uint4*)&ldsU[L_H1 + bb * 264 + sub * 128];
            float ah = 0.f;
#pragma unroll 8
            for (int k4 = 0; k4 < 32; ++k4) {
                const uint4 hv = hp[k4], wv = wh[k4];
                ah = dot2(hv.x, wv.x, ah); ah = dot2(hv.y, wv.y, ah);
                ah = dot2(hv.z, wv.z, ah); ah = dot2(hv.w, wv.w, ah);
            }
            ax += __shfl_down(ax, 1, 2); ah += __shfl_down(ah, 1, 2);
            if (sub == 0) {
                lds[L_AX + gh * 8 + bb] = ax + lds[L_BIH1 + gh];
                lds[L_AH + gh * 8 + bb] = ah + lds[L_BHH1 + gh];
            }
        }
        __syncthreads();
        if (tid < 32) {
            const int hr = tid >> 3, bb = tid & 7;
            const float r = fsig(lds[L_AX + hr * 8 + bb] + lds[L_AH + hr * 8 + bb]);
            const float z = fsig(lds[L_AX + (4 + hr) * 8 + bb] + lds[L_AH + (4 + hr) * 8 + bb]);
            const float n = ftanhf(lds[L_AX + (8 + hr) * 8 + bb] + r * lds[L_AH + (8 + hr) * 8 + bb]);
            U32H u; u.u = ldsU[L_H1 + bb * 264 + j * 2 + (hr >> 1)];
            const float hold = (hr & 1) ? (float)u.h.y : (float)u.h.x;
            lds[L_HS + hr * 8 + bb] = (1.f - z) * n + z * hold;
        }
        __syncthreads();
        if (tid < 16) {
            const int pp = tid >> 3, bb = tid & 7;
            __hip_atomic_store(&h1cU[(par ^ 1) * 4096 + (half * 8 + bb) * 256 + j * 2 + pp],
                               packh2(lds[L_HS + (2 * pp) * 8 + bb], lds[L_HS + (2 * pp + 1) * 8 + bb]),
                               __ATOMIC_RELAXED, __HIP_MEMORY_SCOPE_SYSTEM);
        }
        if (tid < 64) {
            const int f = tid >> 3, bb = tid & 7;
            float acc = 0.f;
#pragma unroll
            for (int hr = 0; hr < 4; ++hr)
                acc += lds[L_OOW + f * 4 + hr] * lds[L_HS + hr * 8 + bb];
            cstore(&outP[((half * 8 + bb) * 128 + j) * 8 + f], acc);
        }
        if (tid < 32) cstore(&weiA[par * 8192 + half * 4096 + j * 32 + tid], 0.f);
        if (sgrp == 0 && tid == 0) cstore(&lacc[par * 16 + b_att], 0.f);
        bar_sync(halfCnt, 128 * (++bars));
    }

    // ---- epilogue: finalize out[31] (par(31) = 1) ----
    if (sgrp == 15 && tid < 64) {
        const int f = tid >> 3, sub = tid & 7;
        float acc = 0.f;
        for (int i = 0; i < 16; ++i)
            acc += cload(&outP[(b_att * 128 + sub * 16 + i) * 8 + f]);
        acc += __shfl_down(acc, 4, 8); acc += __shfl_down(acc, 2, 8); acc += __shfl_down(acc, 1, 8);
        if (sub == 0) {
            acc += cload(&outBs[1 * 128 + b_att * 8 + f]);
            out[b_att * 256 + 31 * 8 + f] = fmaxf(acc, 0.f);
        }
    }
}

extern "C" void kernel_launch(void* const* d_in, const int* in_sizes, int n_in,
                              void* d_out, int out_size, void* d_ws, size_t ws_size,
                              hipStream_t stream) {
    (void)in_sizes; (void)n_in; (void)out_size; (void)ws_size;
    hipMemsetAsync(d_ws, 0, 4096, stream);  // zero barrier counters
    decoder_kernel<<<NBLK, NTHR, 0, stream>>>(
        (const float*)d_in[0], (const float*)d_in[1], (const float*)d_in[2],
        (const float*)d_in[3], (const float*)d_in[4], (const float*)d_in[5],
        (const float*)d_in[6], (const float*)d_in[7], (const float*)d_in[8],
        (const float*)d_in[9], (const float*)d_in[10], (const float*)d_in[11],
        (const float*)d_in[12], (const float*)d_in[13], (const float*)d_in[14],
        (const float*)d_in[15], (float*)d_out, (float*)d_ws);
}